// Round 6
// baseline (1193.952 us; speedup 1.0000x reference)
//
#include <hip/hip_runtime.h>
#include <hip/hip_fp16.h>
#include <math.h>

constexpr int B = 4, N = 4096, D = 256;
constexpr int BN = B * N;
constexpr float EPS = 1e-5f;
// softmax scale (D^-0.5 = 1/16) * log2(e), folded into q at f16-cast time
constexpr float QSC2 = 0.0625f * 1.44269504088896340736f;

constexpr int KB = 32;      // keys per attn tile
constexpr float THR = 8.0f; // defer-max threshold (base-2)
constexpr int PSTR = 32;    // P tile stride in halves (64B)

typedef __attribute__((ext_vector_type(8))) _Float16 f16x8;
typedef __attribute__((ext_vector_type(4))) float f32x4;

__device__ inline f32x4 mfma_f16(f16x8 a, f16x8 b, f32x4 c) {
  return __builtin_amdgcn_mfma_f32_16x16x32_f16(a, b, c, 0, 0, 0);
}
__device__ inline ushort f2h(float x) {
  __half h = __float2half(x);
  return *(ushort*)&h;
}
__device__ inline float h2f(ushort u) {
  __half h;
  *(ushort*)&h = u;
  return __half2float(h);
}
// async global->LDS, 16B per lane; lds dest = uniform base + lane*16 (HW rule)
__device__ inline void gload16(const ushort* g, ushort* l) {
  __builtin_amdgcn_global_load_lds(
      (const __attribute__((address_space(1))) void*)g,
      (__attribute__((address_space(3))) void*)l, 16, 0, 0);
}

// ---------------- LayerNorm -> normalized x as f16 hi/lo planes ------------
__global__ __launch_bounds__(256) void ln_kernel(
    const float* __restrict__ x, const float* __restrict__ g,
    const float* __restrict__ bta, ushort* __restrict__ nxh,
    ushort* __restrict__ nxl) {
  const int row = blockIdx.x;
  const int t = threadIdx.x;
  const float v = x[(size_t)row * D + t];
  float s = v, ss = v * v;
#pragma unroll
  for (int o = 32; o > 0; o >>= 1) {
    s += __shfl_down(s, o);
    ss += __shfl_down(ss, o);
  }
  __shared__ float red[8];
  if ((t & 63) == 0) {
    red[t >> 6] = s;
    red[(t >> 6) + 4] = ss;
  }
  __syncthreads();
  s = red[0] + red[1] + red[2] + red[3];
  ss = red[4] + red[5] + red[6] + red[7];
  const float mu = s * (1.0f / D);
  const float var = ss * (1.0f / D) - mu * mu;
  const float rsig = rsqrtf(var + EPS);
  const float nx = (v - mu) * rsig * g[t] + bta[t];
  const ushort h = f2h(nx);
  nxh[(size_t)row * D + t] = h;
  nxl[(size_t)row * D + t] = f2h(nx - h2f(h));
}

// ------------- cast + transpose weights to f16 (wt[768][256], wot[256][256])
__global__ __launch_bounds__(256) void castw_kernel(
    const float* __restrict__ w_qkv, const float* __restrict__ w_out,
    ushort* __restrict__ wt, ushort* __restrict__ wot) {
  const int id = blockIdx.x * 256 + threadIdx.x;
  if (id < 768 * 256) {
    const int n = id >> 8, k = id & 255;
    wt[id] = f2h(w_qkv[(size_t)k * 768 + n]);
  } else {
    const int j = id - 768 * 256;
    const int n = j >> 8, k = j & 255;
    wot[j] = f2h(w_out[(size_t)k * 256 + n]);
  }
}

// ---------------- QKV GEMM via MFMA (no LDS; weights L2-hot) ---------------
// A = nx (f16 hi/lo planes), W = wt f16 transposed [n][k]. Tile 128x64,
// 4 waves, wave owns 32 rows x 64 cols. acc += Ah*W + Al*W.
__global__ __launch_bounds__(256, 4) void qkv_kernel(
    const ushort* __restrict__ nxh, const ushort* __restrict__ nxl,
    const ushort* __restrict__ wt, const float* __restrict__ coord,
    ushort* __restrict__ qfp, ushort* __restrict__ kfp,
    ushort* __restrict__ vtp) {
  const int t = threadIdx.x;
  const int w = t >> 6, lane = t & 63;
  const int lrow = lane & 15, lhi = lane >> 4;
  const int m0 = blockIdx.x * 128 + w * 32;
  const int c0 = blockIdx.y * 64;  // within [0,768)
  f32x4 acc[2][4];
#pragma unroll
  for (int qs = 0; qs < 2; ++qs)
#pragma unroll
    for (int nt = 0; nt < 4; ++nt) acc[qs][nt] = f32x4{0.f, 0.f, 0.f, 0.f};

#pragma unroll
  for (int kc = 0; kc < D; kc += 32) {
    f16x8 ah[2], al[2], bw[4];
#pragma unroll
    for (int qs = 0; qs < 2; ++qs) {
      const size_t ao = (size_t)(m0 + qs * 16 + lrow) * D + kc + lhi * 8;
      ah[qs] = *(const f16x8*)(nxh + ao);
      al[qs] = *(const f16x8*)(nxl + ao);
    }
#pragma unroll
    for (int nt = 0; nt < 4; ++nt)
      bw[nt] = *(const f16x8*)(wt + (size_t)(c0 + nt * 16 + lrow) * D + kc +
                               lhi * 8);
#pragma unroll
    for (int qs = 0; qs < 2; ++qs)
#pragma unroll
      for (int nt = 0; nt < 4; ++nt) {
        acc[qs][nt] = mfma_f16(ah[qs], bw[nt], acc[qs][nt]);
        acc[qs][nt] = mfma_f16(al[qs], bw[nt], acc[qs][nt]);
      }
  }

  const int region = blockIdx.y >> 2;  // 0:q 1:k 2:v
  const int cbase = c0 & 255;
  if (region < 2) {
    const float sc = (region == 0) ? QSC2 : 1.0f;
    ushort* dp = (region == 0) ? qfp : kfp;
#pragma unroll
    for (int qs = 0; qs < 2; ++qs)
#pragma unroll
      for (int nt = 0; nt < 4; ++nt)
#pragma unroll
        for (int i = 0; i < 4; ++i) {
          const int row = m0 + qs * 16 + lhi * 4 + i;
          const int col = cbase + nt * 16 + lrow;
          const float val =
              (acc[qs][nt][i] + coord[(size_t)row * D + col]) * sc;
          dp[(size_t)row * D + col] = f2h(val);
        }
  } else {
#pragma unroll
    for (int qs = 0; qs < 2; ++qs)
#pragma unroll
      for (int nt = 0; nt < 4; ++nt)
#pragma unroll
        for (int i = 0; i < 4; ++i) {
          const int row = m0 + qs * 16 + lhi * 4 + i;
          const int col = cbase + nt * 16 + lrow;
          const int bb = row >> 12, n = row & (N - 1);
          vtp[((size_t)bb * D + col) * N + n] = f2h(acc[qs][nt][i]);
        }
  }
}

// ---------------- MFMA flash attention ----------------
// 8 waves/block (512 thr), 32 q-rows/wave (QB=256), KB=32 keys/tile.
// LDS exactly 80KB -> 2 blocks/CU (4 waves/SIMD) when grid >= 512.
template <int NSPLIT>
__global__ __launch_bounds__(512, 4) void attn_kernel(
    const ushort* __restrict__ qf, const ushort* __restrict__ kf,
    const ushort* __restrict__ vt, ushort* __restrict__ pob,
    float* __restrict__ mlb) {
  constexpr int NT_ = (N / NSPLIT) / KB;
  __shared__ ushort kbuf[2][8192];
  __shared__ ushort vbuf[2][8192];
  __shared__ ushort ps[8][32 * PSTR];

  const int tid = threadIdx.x;
  const int w = tid >> 6, lane = tid & 63;
  const int lrow = lane & 15, lhi = lane >> 4;
  const int b = blockIdx.y, s = blockIdx.z;
  const int qw = blockIdx.x * 256 + w * 32;
  const int kbeg = s * (N / NSPLIT);

  const ushort* qfb = qf + (size_t)b * N * D;
  const ushort* kfb = kf + (size_t)b * N * D;
  const ushort* vtb = vt + (size_t)b * D * N;
  ushort* pog = pob + (size_t)s * BN * D;
  float* mlg = mlb + (size_t)s * BN * 2;

  f16x8 qfr[2][8];
#pragma unroll
  for (int qs = 0; qs < 2; ++qs)
#pragma unroll
    for (int dc = 0; dc < 8; ++dc)
      qfr[qs][dc] = *(const f16x8*)(
          qfb + (size_t)(qw + qs * 16 + lrow) * D + dc * 32 + lhi * 8);

  f32x4 o[2][16];
  float m[2][4], lsum[2][4];
#pragma unroll
  for (int qs = 0; qs < 2; ++qs) {
#pragma unroll
    for (int i = 0; i < 4; ++i) { m[qs][i] = -1e30f; lsum[qs][i] = 0.f; }
#pragma unroll
    for (int nt = 0; nt < 16; ++nt) o[qs][nt] = f32x4{0.f, 0.f, 0.f, 0.f};
  }

  // chunk c = i*8 + w; K dest c*512 covers [g=c*2+(lane>>5)][key=lane&31];
  // V dest c*512 == (c>>2)*2048 + (c&3)*512 covers [sl=c>>2][d=(c&3)*64+lane].
  auto stage = [&](int bi, int k0) {
#pragma unroll
    for (int i = 0; i < 2; ++i) {
      const int c = i * 8 + w;
      gload16(kfb + (size_t)(k0 + (lane & 31)) * D + (c * 2 + (lane >> 5)) * 8,
              &kbuf[bi][c * 512]);
    }
#pragma unroll
    for (int i = 0; i < 2; ++i) {
      const int c = i * 8 + w;
      gload16(vtb + (size_t)((c & 3) * 64 + lane) * N + k0 + (c >> 2) * 8,
              &vbuf[bi][c * 512]);
    }
  };

  stage(0, kbeg);

  for (int t = 0; t < NT_; ++t) {
    const int cur = t & 1;
    if (t + 1 < NT_) {
      stage(cur ^ 1, kbeg + (t + 1) * KB);
      asm volatile("s_waitcnt vmcnt(4)" ::: "memory");
    } else {
      asm volatile("s_waitcnt vmcnt(0)" ::: "memory");
    }
    __builtin_amdgcn_sched_barrier(0);
    __builtin_amdgcn_s_barrier();
    __builtin_amdgcn_sched_barrier(0);

    // ---- S = Q K^T ----
    f32x4 acc[2][2];
#pragma unroll
    for (int qs = 0; qs < 2; ++qs)
#pragma unroll
      for (int kt = 0; kt < 2; ++kt) acc[qs][kt] = f32x4{0.f, 0.f, 0.f, 0.f};
    __builtin_amdgcn_s_setprio(1);
#pragma unroll
    for (int dc = 0; dc < 8; ++dc)
#pragma unroll
      for (int kt = 0; kt < 2; ++kt) {
        const f16x8 kv = *(const f16x8*)&kbuf[cur][((dc * 4 + lhi) * 32 +
                                                    kt * 16 + lrow) * 8];
        acc[0][kt] = mfma_f16(qfr[0][dc], kv, acc[0][kt]);
        acc[1][kt] = mfma_f16(qfr[1][dc], kv, acc[1][kt]);
      }
    __builtin_amdgcn_s_setprio(0);

    // ---- online softmax, defer-max ----
    float rm[2][4];
    bool need = false;
#pragma unroll
    for (int qs = 0; qs < 2; ++qs)
#pragma unroll
      for (int i = 0; i < 4; ++i) {
        float v = fmaxf(acc[qs][0][i], acc[qs][1][i]);
#pragma unroll
        for (int off = 1; off < 16; off <<= 1) v = fmaxf(v, __shfl_xor(v, off));
        rm[qs][i] = v;
        need |= (v > m[qs][i] + THR);
      }
    if (__any(need)) {
#pragma unroll
      for (int qs = 0; qs < 2; ++qs)
#pragma unroll
        for (int i = 0; i < 4; ++i) {
          const float mn = fmaxf(m[qs][i], rm[qs][i]);
          const float f = exp2f(m[qs][i] - mn);
          m[qs][i] = mn;
          lsum[qs][i] *= f;
#pragma unroll
          for (int nt = 0; nt < 16; ++nt) o[qs][nt][i] *= f;
        }
    }
#pragma unroll
    for (int qs = 0; qs < 2; ++qs)
#pragma unroll
      for (int kt = 0; kt < 2; ++kt)
#pragma unroll
        for (int i = 0; i < 4; ++i) {
          const float p = exp2f(acc[qs][kt][i] - m[qs][i]);
          lsum[qs][i] += p;
          ps[w][(qs * 16 + lhi * 4 + i) * PSTR + kt * 16 + lrow] = f2h(p);
        }
    asm volatile("s_waitcnt lgkmcnt(0)" ::: "memory");
    __builtin_amdgcn_sched_barrier(0);

    // ---- O += P V ----
    const f16x8 pf0 = *(const f16x8*)&ps[w][lrow * PSTR + lhi * 8];
    const f16x8 pf1 = *(const f16x8*)&ps[w][(16 + lrow) * PSTR + lhi * 8];
    __builtin_amdgcn_s_setprio(1);
#pragma unroll
    for (int nt = 0; nt < 16; ++nt) {
      const f16x8 vv =
          *(const f16x8*)&vbuf[cur][lhi * 2048 + (nt * 16 + lrow) * 8];
      o[0][nt] = mfma_f16(pf0, vv, o[0][nt]);
      o[1][nt] = mfma_f16(pf1, vv, o[1][nt]);
    }
    __builtin_amdgcn_s_setprio(0);
    __builtin_amdgcn_s_barrier();
    __builtin_amdgcn_sched_barrier(0);
  }

  // ---- epilogue ----
#pragma unroll
  for (int qs = 0; qs < 2; ++qs)
#pragma unroll
    for (int i = 0; i < 4; ++i) {
      float v = lsum[qs][i];
#pragma unroll
      for (int off = 1; off < 16; off <<= 1) v += __shfl_xor(v, off);
      lsum[qs][i] = v;
    }
  float inv[2][4];
#pragma unroll
  for (int qs = 0; qs < 2; ++qs)
#pragma unroll
    for (int i = 0; i < 4; ++i) inv[qs][i] = 1.0f / lsum[qs][i];
#pragma unroll
  for (int qs = 0; qs < 2; ++qs)
#pragma unroll
    for (int nt = 0; nt < 16; ++nt)
#pragma unroll
      for (int i = 0; i < 4; ++i)
        pog[((size_t)b * N + qw + qs * 16 + lhi * 4 + i) * D + nt * 16 + lrow] =
            f2h(o[qs][nt][i] * inv[qs][i]);
  if (lrow == 0) {
#pragma unroll
    for (int qs = 0; qs < 2; ++qs)
#pragma unroll
      for (int i = 0; i < 4; ++i) {
        const size_t r = (size_t)b * N + qw + qs * 16 + lhi * 4 + i;
        mlg[r * 2] = m[qs][i];
        mlg[r * 2 + 1] = lsum[qs][i];
      }
  }
}

// ---------------- merge KV-split partials -> f16 hi/lo planes --------------
template <int NSPLIT>
__global__ __launch_bounds__(256) void merge_kernel(
    const ushort* __restrict__ pob, const float* __restrict__ mlb,
    ushort* __restrict__ aoh, ushort* __restrict__ aol) {
  const int t = threadIdx.x;
  const int row = blockIdx.x * 8 + (t >> 5);
  const int d0 = (t & 31) * 8;
  float mv[NSPLIT], lv[NSPLIT];
  float mm = -1e30f;
#pragma unroll
  for (int s = 0; s < NSPLIT; ++s) {
    mv[s] = mlb[(size_t)s * BN * 2 + row * 2];
    lv[s] = mlb[(size_t)s * BN * 2 + row * 2 + 1];
    mm = fmaxf(mm, mv[s]);
  }
  float wsum = 0.f, a[NSPLIT];
#pragma unroll
  for (int s = 0; s < NSPLIT; ++s) {
    a[s] = exp2f(mv[s] - mm) * lv[s];
    wsum += a[s];
  }
  const float invw = 1.0f / wsum;
  const size_t off = (size_t)row * D + d0;
  float r[8] = {};
#pragma unroll
  for (int s = 0; s < NSPLIT; ++s) {
    const f16x8 p = *(const f16x8*)(pob + (size_t)s * BN * D + off);
    const float c = a[s] * invw;
#pragma unroll
    for (int j = 0; j < 8; ++j) r[j] += c * (float)p[j];
  }
  f16x8 rh, rl;
#pragma unroll
  for (int j = 0; j < 8; ++j) {
    rh[j] = (_Float16)r[j];
    rl[j] = (_Float16)(r[j] - (float)rh[j]);
  }
  *(f16x8*)(aoh + off) = rh;
  *(f16x8*)(aol + off) = rl;
}

// ---------------- output projection via MFMA (no LDS) ----------------
__global__ __launch_bounds__(256, 4) void proj_kernel(
    const ushort* __restrict__ aoh, const ushort* __restrict__ aol,
    const ushort* __restrict__ wot, const float* __restrict__ bias,
    float* __restrict__ out) {
  const int t = threadIdx.x;
  const int w = t >> 6, lane = t & 63;
  const int lrow = lane & 15, lhi = lane >> 4;
  const int m0 = blockIdx.x * 128 + w * 32;
  const int c0 = blockIdx.y * 64;
  f32x4 acc[2][4];
#pragma unroll
  for (int qs = 0; qs < 2; ++qs)
#pragma unroll
    for (int nt = 0; nt < 4; ++nt) acc[qs][nt] = f32x4{0.f, 0.f, 0.f, 0.f};

#pragma unroll
  for (int kc = 0; kc < D; kc += 32) {
    f16x8 ah[2], al[2], bw[4];
#pragma unroll
    for (int qs = 0; qs < 2; ++qs) {
      const size_t ao = (size_t)(m0 + qs * 16 + lrow) * D + kc + lhi * 8;
      ah[qs] = *(const f16x8*)(aoh + ao);
      al[qs] = *(const f16x8*)(aol + ao);
    }
#pragma unroll
    for (int nt = 0; nt < 4; ++nt)
      bw[nt] = *(const f16x8*)(wot + (size_t)(c0 + nt * 16 + lrow) * D + kc +
                               lhi * 8);
#pragma unroll
    for (int qs = 0; qs < 2; ++qs)
#pragma unroll
      for (int nt = 0; nt < 4; ++nt) {
        acc[qs][nt] = mfma_f16(ah[qs], bw[nt], acc[qs][nt]);
        acc[qs][nt] = mfma_f16(al[qs], bw[nt], acc[qs][nt]);
      }
  }
#pragma unroll
  for (int qs = 0; qs < 2; ++qs)
#pragma unroll
    for (int nt = 0; nt < 4; ++nt)
#pragma unroll
      for (int i = 0; i < 4; ++i) {
        const int row = m0 + qs * 16 + lhi * 4 + i;
        const int col = c0 + nt * 16 + lrow;
        out[(size_t)row * D + col] = acc[qs][nt][i] + bias[col];
      }
}

extern "C" void kernel_launch(void* const* d_in, const int* in_sizes, int n_in,
                              void* d_out, int out_size, void* d_ws, size_t ws_size,
                              hipStream_t stream) {
  const float* x = (const float*)d_in[0];
  const float* coord = (const float*)d_in[1];
  const float* ln_g = (const float*)d_in[2];
  const float* ln_b = (const float*)d_in[3];
  const float* w_qkv = (const float*)d_in[4];
  const float* w_out = (const float*)d_in[5];
  const float* b_out = (const float*)d_in[6];
  float* out = (float*)d_out;

  const size_t P = (size_t)BN * D;
  const size_t WELEM = 768 * 256 + 256 * 256;
  // bytes needed for SPLIT=8: (3P + 8P + WELEM)*2 + 8*BN*2*4
  const size_t need8 = (11 * P + WELEM) * 2 + (size_t)8 * BN * 2 * 4;
  const int SPLIT = (ws_size >= need8) ? 8 : 4;

  ushort* qfp = (ushort*)d_ws;
  ushort* kfp = qfp + P;
  ushort* vtp = kfp + P;
  ushort* pob = vtp + P;                      // NSPLIT partial-O planes
  float* mlb = (float*)(pob + (size_t)SPLIT * P);
  ushort* wt = (ushort*)(mlb + (size_t)SPLIT * BN * 2);
  ushort* wot = wt + 768 * 256;
  // aliases (liveness-disjoint):
  ushort* nxh = pob;       // written by ln, consumed by qkv, dead before attn
  ushort* nxl = pob + P;
  ushort* aoh = qfp;       // written by merge after q/k are dead
  ushort* aol = kfp;

  hipLaunchKernelGGL(ln_kernel, dim3(BN), dim3(256), 0, stream,
                     x, ln_g, ln_b, nxh, nxl);
  hipLaunchKernelGGL(castw_kernel, dim3(1024), dim3(256), 0, stream,
                     w_qkv, w_out, wt, wot);
  hipLaunchKernelGGL(qkv_kernel, dim3(BN / 128, 12), dim3(256), 0, stream,
                     nxh, nxl, wt, coord, qfp, kfp, vtp);
  if (SPLIT == 8) {
    hipLaunchKernelGGL((attn_kernel<8>), dim3(N / 256, B, 8), dim3(512), 0,
                       stream, qfp, kfp, vtp, pob, mlb);
    hipLaunchKernelGGL((merge_kernel<8>), dim3(BN / 8), dim3(256), 0, stream,
                       pob, mlb, aoh, aol);
  } else {
    hipLaunchKernelGGL((attn_kernel<4>), dim3(N / 256, B, 4), dim3(512), 0,
                       stream, qfp, kfp, vtp, pob, mlb);
    hipLaunchKernelGGL((merge_kernel<4>), dim3(BN / 8), dim3(256), 0, stream,
                       pob, mlb, aoh, aol);
  }
  hipLaunchKernelGGL(proj_kernel, dim3(BN / 128, 4), dim3(256), 0, stream,
                     aoh, aol, wot, b_out, out);
}

// Round 7
// 269.942 us; speedup vs baseline: 4.4230x; 4.4230x over previous
//
#include <hip/hip_runtime.h>
#include <hip/hip_fp16.h>
#include <math.h>

constexpr int B = 4, N = 4096, D = 256;
constexpr int BN = B * N;
constexpr float EPS = 1e-5f;
// softmax scale (D^-0.5 = 1/16) * log2(e), folded into q at f16-cast time
constexpr float QSC2 = 0.0625f * 1.44269504088896340736f;

constexpr int KB = 32;      // keys per attn tile
constexpr float THR = 8.0f; // defer-max threshold (base-2)
constexpr int PSTR = 32;    // P tile stride in halves (64B)

typedef __attribute__((ext_vector_type(8))) _Float16 f16x8;
typedef __attribute__((ext_vector_type(4))) float f32x4;

__device__ inline f32x4 mfma_f16(f16x8 a, f16x8 b, f32x4 c) {
  return __builtin_amdgcn_mfma_f32_16x16x32_f16(a, b, c, 0, 0, 0);
}
__device__ inline ushort f2h(float x) {
  __half h = __float2half(x);
  return *(ushort*)&h;
}
__device__ inline float h2f(ushort u) {
  __half h;
  *(ushort*)&h = u;
  return __half2float(h);
}
// async global->LDS, 16B per lane; lds dest = uniform base + lane*16 (HW rule)
__device__ inline void gload16(const ushort* g, ushort* l) {
  __builtin_amdgcn_global_load_lds(
      (const __attribute__((address_space(1))) void*)g,
      (__attribute__((address_space(3))) void*)l, 16, 0, 0);
}

// ---------------- LayerNorm -> normalized x as f16 hi/lo planes ------------
__global__ __launch_bounds__(256) void ln_kernel(
    const float* __restrict__ x, const float* __restrict__ g,
    const float* __restrict__ bta, ushort* __restrict__ nxh,
    ushort* __restrict__ nxl) {
  const int row = blockIdx.x;
  const int t = threadIdx.x;
  const float v = x[(size_t)row * D + t];
  float s = v, ss = v * v;
#pragma unroll
  for (int o = 32; o > 0; o >>= 1) {
    s += __shfl_down(s, o);
    ss += __shfl_down(ss, o);
  }
  __shared__ float red[8];
  if ((t & 63) == 0) {
    red[t >> 6] = s;
    red[(t >> 6) + 4] = ss;
  }
  __syncthreads();
  s = red[0] + red[1] + red[2] + red[3];
  ss = red[4] + red[5] + red[6] + red[7];
  const float mu = s * (1.0f / D);
  const float var = ss * (1.0f / D) - mu * mu;
  const float rsig = rsqrtf(var + EPS);
  const float nx = (v - mu) * rsig * g[t] + bta[t];
  const ushort h = f2h(nx);
  nxh[(size_t)row * D + t] = h;
  nxl[(size_t)row * D + t] = f2h(nx - h2f(h));
}

// ------------- cast + transpose weights to f16 (wt[768][256], wot[256][256])
__global__ __launch_bounds__(256) void castw_kernel(
    const float* __restrict__ w_qkv, const float* __restrict__ w_out,
    ushort* __restrict__ wt, ushort* __restrict__ wot) {
  const int id = blockIdx.x * 256 + threadIdx.x;
  if (id < 768 * 256) {
    const int n = id >> 8, k = id & 255;
    wt[id] = f2h(w_qkv[(size_t)k * 768 + n]);
  } else {
    const int j = id - 768 * 256;
    const int n = j >> 8, k = j & 255;
    wot[j] = f2h(w_out[(size_t)k * 256 + n]);
  }
}

// ---------------- QKV GEMM via MFMA (no LDS; weights L2-hot) ---------------
// A = nx (f16 hi/lo planes), W = wt f16 transposed [n][k]. Tile 128x64,
// 4 waves, wave owns 32 rows x 64 cols. acc += Ah*W + Al*W.
__global__ __launch_bounds__(256, 4) void qkv_kernel(
    const ushort* __restrict__ nxh, const ushort* __restrict__ nxl,
    const ushort* __restrict__ wt, const float* __restrict__ coord,
    ushort* __restrict__ qfp, ushort* __restrict__ kfp,
    ushort* __restrict__ vtp) {
  const int t = threadIdx.x;
  const int w = t >> 6, lane = t & 63;
  const int lrow = lane & 15, lhi = lane >> 4;
  const int m0 = blockIdx.x * 128 + w * 32;
  const int c0 = blockIdx.y * 64;  // within [0,768)
  f32x4 acc[2][4];
#pragma unroll
  for (int qs = 0; qs < 2; ++qs)
#pragma unroll
    for (int nt = 0; nt < 4; ++nt) acc[qs][nt] = f32x4{0.f, 0.f, 0.f, 0.f};

#pragma unroll
  for (int kc = 0; kc < D; kc += 32) {
    f16x8 ah[2], al[2], bw[4];
#pragma unroll
    for (int qs = 0; qs < 2; ++qs) {
      const size_t ao = (size_t)(m0 + qs * 16 + lrow) * D + kc + lhi * 8;
      ah[qs] = *(const f16x8*)(nxh + ao);
      al[qs] = *(const f16x8*)(nxl + ao);
    }
#pragma unroll
    for (int nt = 0; nt < 4; ++nt)
      bw[nt] = *(const f16x8*)(wt + (size_t)(c0 + nt * 16 + lrow) * D + kc +
                               lhi * 8);
#pragma unroll
    for (int qs = 0; qs < 2; ++qs)
#pragma unroll
      for (int nt = 0; nt < 4; ++nt) {
        acc[qs][nt] = mfma_f16(ah[qs], bw[nt], acc[qs][nt]);
        acc[qs][nt] = mfma_f16(al[qs], bw[nt], acc[qs][nt]);
      }
  }

  const int region = blockIdx.y >> 2;  // 0:q 1:k 2:v
  const int cbase = c0 & 255;
  if (region < 2) {
    const float sc = (region == 0) ? QSC2 : 1.0f;
    ushort* dp = (region == 0) ? qfp : kfp;
#pragma unroll
    for (int qs = 0; qs < 2; ++qs)
#pragma unroll
      for (int nt = 0; nt < 4; ++nt)
#pragma unroll
        for (int i = 0; i < 4; ++i) {
          const int row = m0 + qs * 16 + lhi * 4 + i;
          const int col = cbase + nt * 16 + lrow;
          const float val =
              (acc[qs][nt][i] + coord[(size_t)row * D + col]) * sc;
          dp[(size_t)row * D + col] = f2h(val);
        }
  } else {
#pragma unroll
    for (int qs = 0; qs < 2; ++qs)
#pragma unroll
      for (int nt = 0; nt < 4; ++nt)
#pragma unroll
        for (int i = 0; i < 4; ++i) {
          const int row = m0 + qs * 16 + lhi * 4 + i;
          const int col = cbase + nt * 16 + lrow;
          const int bb = row >> 12, n = row & (N - 1);
          vtp[((size_t)bb * D + col) * N + n] = f2h(acc[qs][nt][i]);
        }
  }
}

// ---------------- MFMA flash attention ----------------
// 8 waves/block (512 thr), 32 q-rows/wave (QB=256), KB=32 keys/tile.
// LDS exactly 80KB; natural VGPR ~128 -> HW can co-schedule 2 blocks/CU
// (4 waves/SIMD). NOTE: launch_bounds min-waves stays 2 — forcing 4 caps
// VGPRs at 64 and spills the O accumulator (round-6 regression: 1.7GB
// scratch traffic, 6x slowdown).
template <int NSPLIT>
__global__ __launch_bounds__(512, 2) void attn_kernel(
    const ushort* __restrict__ qf, const ushort* __restrict__ kf,
    const ushort* __restrict__ vt, ushort* __restrict__ pob,
    float* __restrict__ mlb) {
  constexpr int NT_ = (N / NSPLIT) / KB;
  __shared__ ushort kbuf[2][8192];
  __shared__ ushort vbuf[2][8192];
  __shared__ ushort ps[8][32 * PSTR];

  const int tid = threadIdx.x;
  const int w = tid >> 6, lane = tid & 63;
  const int lrow = lane & 15, lhi = lane >> 4;
  const int b = blockIdx.y, s = blockIdx.z;
  const int qw = blockIdx.x * 256 + w * 32;
  const int kbeg = s * (N / NSPLIT);

  const ushort* qfb = qf + (size_t)b * N * D;
  const ushort* kfb = kf + (size_t)b * N * D;
  const ushort* vtb = vt + (size_t)b * D * N;
  ushort* pog = pob + (size_t)s * BN * D;
  float* mlg = mlb + (size_t)s * BN * 2;

  f16x8 qfr[2][8];
#pragma unroll
  for (int qs = 0; qs < 2; ++qs)
#pragma unroll
    for (int dc = 0; dc < 8; ++dc)
      qfr[qs][dc] = *(const f16x8*)(
          qfb + (size_t)(qw + qs * 16 + lrow) * D + dc * 32 + lhi * 8);

  f32x4 o[2][16];
  float m[2][4], lsum[2][4];
#pragma unroll
  for (int qs = 0; qs < 2; ++qs) {
#pragma unroll
    for (int i = 0; i < 4; ++i) { m[qs][i] = -1e30f; lsum[qs][i] = 0.f; }
#pragma unroll
    for (int nt = 0; nt < 16; ++nt) o[qs][nt] = f32x4{0.f, 0.f, 0.f, 0.f};
  }

  // chunk c = i*8 + w; K dest c*512 covers [g=c*2+(lane>>5)][key=lane&31];
  // V dest c*512 == (c>>2)*2048 + (c&3)*512 covers [sl=c>>2][d=(c&3)*64+lane].
  auto stage = [&](int bi, int k0) {
#pragma unroll
    for (int i = 0; i < 2; ++i) {
      const int c = i * 8 + w;
      gload16(kfb + (size_t)(k0 + (lane & 31)) * D + (c * 2 + (lane >> 5)) * 8,
              &kbuf[bi][c * 512]);
    }
#pragma unroll
    for (int i = 0; i < 2; ++i) {
      const int c = i * 8 + w;
      gload16(vtb + (size_t)((c & 3) * 64 + lane) * N + k0 + (c >> 2) * 8,
              &vbuf[bi][c * 512]);
    }
  };

  stage(0, kbeg);

  for (int t = 0; t < NT_; ++t) {
    const int cur = t & 1;
    if (t + 1 < NT_) {
      stage(cur ^ 1, kbeg + (t + 1) * KB);
      asm volatile("s_waitcnt vmcnt(4)" ::: "memory");
    } else {
      asm volatile("s_waitcnt vmcnt(0)" ::: "memory");
    }
    __builtin_amdgcn_sched_barrier(0);
    __builtin_amdgcn_s_barrier();
    __builtin_amdgcn_sched_barrier(0);

    // ---- S = Q K^T ----
    f32x4 acc[2][2];
#pragma unroll
    for (int qs = 0; qs < 2; ++qs)
#pragma unroll
      for (int kt = 0; kt < 2; ++kt) acc[qs][kt] = f32x4{0.f, 0.f, 0.f, 0.f};
    __builtin_amdgcn_s_setprio(1);
#pragma unroll
    for (int dc = 0; dc < 8; ++dc)
#pragma unroll
      for (int kt = 0; kt < 2; ++kt) {
        const f16x8 kv = *(const f16x8*)&kbuf[cur][((dc * 4 + lhi) * 32 +
                                                    kt * 16 + lrow) * 8];
        acc[0][kt] = mfma_f16(qfr[0][dc], kv, acc[0][kt]);
        acc[1][kt] = mfma_f16(qfr[1][dc], kv, acc[1][kt]);
      }
    __builtin_amdgcn_s_setprio(0);

    // ---- online softmax, defer-max ----
    float rm[2][4];
    bool need = false;
#pragma unroll
    for (int qs = 0; qs < 2; ++qs)
#pragma unroll
      for (int i = 0; i < 4; ++i) {
        float v = fmaxf(acc[qs][0][i], acc[qs][1][i]);
#pragma unroll
        for (int off = 1; off < 16; off <<= 1) v = fmaxf(v, __shfl_xor(v, off));
        rm[qs][i] = v;
        need |= (v > m[qs][i] + THR);
      }
    if (__any(need)) {
#pragma unroll
      for (int qs = 0; qs < 2; ++qs)
#pragma unroll
        for (int i = 0; i < 4; ++i) {
          const float mn = fmaxf(m[qs][i], rm[qs][i]);
          const float f = exp2f(m[qs][i] - mn);
          m[qs][i] = mn;
          lsum[qs][i] *= f;
#pragma unroll
          for (int nt = 0; nt < 16; ++nt) o[qs][nt][i] *= f;
        }
    }
#pragma unroll
    for (int qs = 0; qs < 2; ++qs)
#pragma unroll
      for (int kt = 0; kt < 2; ++kt)
#pragma unroll
        for (int i = 0; i < 4; ++i) {
          const float p = exp2f(acc[qs][kt][i] - m[qs][i]);
          lsum[qs][i] += p;
          ps[w][(qs * 16 + lhi * 4 + i) * PSTR + kt * 16 + lrow] = f2h(p);
        }
    asm volatile("s_waitcnt lgkmcnt(0)" ::: "memory");
    __builtin_amdgcn_sched_barrier(0);

    // ---- O += P V ----
    const f16x8 pf0 = *(const f16x8*)&ps[w][lrow * PSTR + lhi * 8];
    const f16x8 pf1 = *(const f16x8*)&ps[w][(16 + lrow) * PSTR + lhi * 8];
    __builtin_amdgcn_s_setprio(1);
#pragma unroll
    for (int nt = 0; nt < 16; ++nt) {
      const f16x8 vv =
          *(const f16x8*)&vbuf[cur][lhi * 2048 + (nt * 16 + lrow) * 8];
      o[0][nt] = mfma_f16(pf0, vv, o[0][nt]);
      o[1][nt] = mfma_f16(pf1, vv, o[1][nt]);
    }
    __builtin_amdgcn_s_setprio(0);
    __builtin_amdgcn_s_barrier();
    __builtin_amdgcn_sched_barrier(0);
  }

  // ---- epilogue ----
#pragma unroll
  for (int qs = 0; qs < 2; ++qs)
#pragma unroll
    for (int i = 0; i < 4; ++i) {
      float v = lsum[qs][i];
#pragma unroll
      for (int off = 1; off < 16; off <<= 1) v += __shfl_xor(v, off);
      lsum[qs][i] = v;
    }
  float inv[2][4];
#pragma unroll
  for (int qs = 0; qs < 2; ++qs)
#pragma unroll
    for (int i = 0; i < 4; ++i) inv[qs][i] = 1.0f / lsum[qs][i];
#pragma unroll
  for (int qs = 0; qs < 2; ++qs)
#pragma unroll
    for (int nt = 0; nt < 16; ++nt)
#pragma unroll
      for (int i = 0; i < 4; ++i)
        pog[((size_t)b * N + qw + qs * 16 + lhi * 4 + i) * D + nt * 16 + lrow] =
            f2h(o[qs][nt][i] * inv[qs][i]);
  if (lrow == 0) {
#pragma unroll
    for (int qs = 0; qs < 2; ++qs)
#pragma unroll
      for (int i = 0; i < 4; ++i) {
        const size_t r = (size_t)b * N + qw + qs * 16 + lhi * 4 + i;
        mlg[r * 2] = m[qs][i];
        mlg[r * 2 + 1] = lsum[qs][i];
      }
  }
}

// ---------------- merge KV-split partials -> f16 hi/lo planes --------------
template <int NSPLIT>
__global__ __launch_bounds__(256) void merge_kernel(
    const ushort* __restrict__ pob, const float* __restrict__ mlb,
    ushort* __restrict__ aoh, ushort* __restrict__ aol) {
  const int t = threadIdx.x;
  const int row = blockIdx.x * 8 + (t >> 5);
  const int d0 = (t & 31) * 8;
  float mv[NSPLIT], lv[NSPLIT];
  float mm = -1e30f;
#pragma unroll
  for (int s = 0; s < NSPLIT; ++s) {
    mv[s] = mlb[(size_t)s * BN * 2 + row * 2];
    lv[s] = mlb[(size_t)s * BN * 2 + row * 2 + 1];
    mm = fmaxf(mm, mv[s]);
  }
  float wsum = 0.f, a[NSPLIT];
#pragma unroll
  for (int s = 0; s < NSPLIT; ++s) {
    a[s] = exp2f(mv[s] - mm) * lv[s];
    wsum += a[s];
  }
  const float invw = 1.0f / wsum;
  const size_t off = (size_t)row * D + d0;
  float r[8] = {};
#pragma unroll
  for (int s = 0; s < NSPLIT; ++s) {
    const f16x8 p = *(const f16x8*)(pob + (size_t)s * BN * D + off);
    const float c = a[s] * invw;
#pragma unroll
    for (int j = 0; j < 8; ++j) r[j] += c * (float)p[j];
  }
  f16x8 rh, rl;
#pragma unroll
  for (int j = 0; j < 8; ++j) {
    rh[j] = (_Float16)r[j];
    rl[j] = (_Float16)(r[j] - (float)rh[j]);
  }
  *(f16x8*)(aoh + off) = rh;
  *(f16x8*)(aol + off) = rl;
}

// ---------------- output projection via MFMA (no LDS) ----------------
__global__ __launch_bounds__(256, 4) void proj_kernel(
    const ushort* __restrict__ aoh, const ushort* __restrict__ aol,
    const ushort* __restrict__ wot, const float* __restrict__ bias,
    float* __restrict__ out) {
  const int t = threadIdx.x;
  const int w = t >> 6, lane = t & 63;
  const int lrow = lane & 15, lhi = lane >> 4;
  const int m0 = blockIdx.x * 128 + w * 32;
  const int c0 = blockIdx.y * 64;
  f32x4 acc[2][4];
#pragma unroll
  for (int qs = 0; qs < 2; ++qs)
#pragma unroll
    for (int nt = 0; nt < 4; ++nt) acc[qs][nt] = f32x4{0.f, 0.f, 0.f, 0.f};

#pragma unroll
  for (int kc = 0; kc < D; kc += 32) {
    f16x8 ah[2], al[2], bw[4];
#pragma unroll
    for (int qs = 0; qs < 2; ++qs) {
      const size_t ao = (size_t)(m0 + qs * 16 + lrow) * D + kc + lhi * 8;
      ah[qs] = *(const f16x8*)(aoh + ao);
      al[qs] = *(const f16x8*)(aol + ao);
    }
#pragma unroll
    for (int nt = 0; nt < 4; ++nt)
      bw[nt] = *(const f16x8*)(wot + (size_t)(c0 + nt * 16 + lrow) * D + kc +
                               lhi * 8);
#pragma unroll
    for (int qs = 0; qs < 2; ++qs)
#pragma unroll
      for (int nt = 0; nt < 4; ++nt) {
        acc[qs][nt] = mfma_f16(ah[qs], bw[nt], acc[qs][nt]);
        acc[qs][nt] = mfma_f16(al[qs], bw[nt], acc[qs][nt]);
      }
  }
#pragma unroll
  for (int qs = 0; qs < 2; ++qs)
#pragma unroll
    for (int nt = 0; nt < 4; ++nt)
#pragma unroll
      for (int i = 0; i < 4; ++i) {
        const int row = m0 + qs * 16 + lhi * 4 + i;
        const int col = c0 + nt * 16 + lrow;
        out[(size_t)row * D + col] = acc[qs][nt][i] + bias[col];
      }
}

extern "C" void kernel_launch(void* const* d_in, const int* in_sizes, int n_in,
                              void* d_out, int out_size, void* d_ws, size_t ws_size,
                              hipStream_t stream) {
  const float* x = (const float*)d_in[0];
  const float* coord = (const float*)d_in[1];
  const float* ln_g = (const float*)d_in[2];
  const float* ln_b = (const float*)d_in[3];
  const float* w_qkv = (const float*)d_in[4];
  const float* w_out = (const float*)d_in[5];
  const float* b_out = (const float*)d_in[6];
  float* out = (float*)d_out;

  const size_t P = (size_t)BN * D;
  const size_t WELEM = 768 * 256 + 256 * 256;
  // bytes needed for SPLIT=8: (3P + 8P + WELEM)*2 + 8*BN*2*4
  const size_t need8 = (11 * P + WELEM) * 2 + (size_t)8 * BN * 2 * 4;
  const int SPLIT = (ws_size >= need8) ? 8 : 4;

  ushort* qfp = (ushort*)d_ws;
  ushort* kfp = qfp + P;
  ushort* vtp = kfp + P;
  ushort* pob = vtp + P;                      // NSPLIT partial-O planes
  float* mlb = (float*)(pob + (size_t)SPLIT * P);
  ushort* wt = (ushort*)(mlb + (size_t)SPLIT * BN * 2);
  ushort* wot = wt + 768 * 256;
  // aliases (liveness-disjoint):
  ushort* nxh = pob;       // written by ln, consumed by qkv, dead before attn
  ushort* nxl = pob + P;
  ushort* aoh = qfp;       // written by merge after q/k are dead
  ushort* aol = kfp;

  hipLaunchKernelGGL(ln_kernel, dim3(BN), dim3(256), 0, stream,
                     x, ln_g, ln_b, nxh, nxl);
  hipLaunchKernelGGL(castw_kernel, dim3(1024), dim3(256), 0, stream,
                     w_qkv, w_out, wt, wot);
  hipLaunchKernelGGL(qkv_kernel, dim3(BN / 128, 12), dim3(256), 0, stream,
                     nxh, nxl, wt, coord, qfp, kfp, vtp);
  if (SPLIT == 8) {
    hipLaunchKernelGGL((attn_kernel<8>), dim3(N / 256, B, 8), dim3(512), 0,
                       stream, qfp, kfp, vtp, pob, mlb);
    hipLaunchKernelGGL((merge_kernel<8>), dim3(BN / 8), dim3(256), 0, stream,
                       pob, mlb, aoh, aol);
  } else {
    hipLaunchKernelGGL((attn_kernel<4>), dim3(N / 256, B, 4), dim3(512), 0,
                       stream, qfp, kfp, vtp, pob, mlb);
    hipLaunchKernelGGL((merge_kernel<4>), dim3(BN / 8), dim3(256), 0, stream,
                       pob, mlb, aoh, aol);
  }
  hipLaunchKernelGGL(proj_kernel, dim3(BN / 128, 4), dim3(256), 0, stream,
                     aoh, aol, wot, b_out, out);
}

// Round 8
// 269.721 us; speedup vs baseline: 4.4266x; 1.0008x over previous
//
#include <hip/hip_runtime.h>
#include <hip/hip_fp16.h>
#include <math.h>

constexpr int B = 4, N = 4096, D = 256;
constexpr int BN = B * N;
constexpr float EPS = 1e-5f;
// softmax scale (D^-0.5 = 1/16) * log2(e), folded into q at f16-cast time
constexpr float QSC2 = 0.0625f * 1.44269504088896340736f;

constexpr int SPLIT = 4;    // KV splits (grid = 512 blocks = 2/CU)
constexpr int KB = 32;      // keys per attn tile
constexpr int NT = (N / SPLIT) / KB;
constexpr float THR = 8.0f; // defer-max threshold (base-2)
constexpr int PSTR = 36;    // P stride in halves (72B): lhi groups 8 banks apart

typedef __attribute__((ext_vector_type(8))) _Float16 f16x8;
typedef __attribute__((ext_vector_type(4))) float f32x4;

__device__ inline f32x4 mfma_f16(f16x8 a, f16x8 b, f32x4 c) {
  return __builtin_amdgcn_mfma_f32_16x16x32_f16(a, b, c, 0, 0, 0);
}
__device__ inline ushort f2h(float x) {
  __half h = __float2half(x);
  return *(ushort*)&h;
}
__device__ inline float h2f(ushort u) {
  __half h;
  *(ushort*)&h = u;
  return __half2float(h);
}
// async global->LDS, 16B per lane; lds dest = uniform base + lane*16 (HW rule)
__device__ inline void gload16(const ushort* g, ushort* l) {
  __builtin_amdgcn_global_load_lds(
      (const __attribute__((address_space(1))) void*)g,
      (__attribute__((address_space(3))) void*)l, 16, 0, 0);
}

// ---------------- LayerNorm -> normalized x as f16 hi/lo planes ------------
__global__ __launch_bounds__(256) void ln_kernel(
    const float* __restrict__ x, const float* __restrict__ g,
    const float* __restrict__ bta, ushort* __restrict__ nxh,
    ushort* __restrict__ nxl) {
  const int row = blockIdx.x;
  const int t = threadIdx.x;
  const float v = x[(size_t)row * D + t];
  float s = v, ss = v * v;
#pragma unroll
  for (int o = 32; o > 0; o >>= 1) {
    s += __shfl_down(s, o);
    ss += __shfl_down(ss, o);
  }
  __shared__ float red[8];
  if ((t & 63) == 0) {
    red[t >> 6] = s;
    red[(t >> 6) + 4] = ss;
  }
  __syncthreads();
  s = red[0] + red[1] + red[2] + red[3];
  ss = red[4] + red[5] + red[6] + red[7];
  const float mu = s * (1.0f / D);
  const float var = ss * (1.0f / D) - mu * mu;
  const float rsig = rsqrtf(var + EPS);
  const float nx = (v - mu) * rsig * g[t] + bta[t];
  const ushort h = f2h(nx);
  nxh[(size_t)row * D + t] = h;
  nxl[(size_t)row * D + t] = f2h(nx - h2f(h));
}

// ------------- cast + transpose weights to f16 (wt[768][256], wot[256][256])
__global__ __launch_bounds__(256) void castw_kernel(
    const float* __restrict__ w_qkv, const float* __restrict__ w_out,
    ushort* __restrict__ wt, ushort* __restrict__ wot) {
  const int id = blockIdx.x * 256 + threadIdx.x;
  if (id < 768 * 256) {
    const int n = id >> 8, k = id & 255;
    wt[id] = f2h(w_qkv[(size_t)k * 768 + n]);
  } else {
    const int j = id - 768 * 256;
    const int n = j >> 8, k = j & 255;
    wot[j] = f2h(w_out[(size_t)k * 256 + n]);
  }
}

// ---------------- QKV GEMM via MFMA (no LDS; weights L2-hot) ---------------
__global__ __launch_bounds__(256, 4) void qkv_kernel(
    const ushort* __restrict__ nxh, const ushort* __restrict__ nxl,
    const ushort* __restrict__ wt, const float* __restrict__ coord,
    ushort* __restrict__ qfp, ushort* __restrict__ kfp,
    ushort* __restrict__ vtp) {
  const int t = threadIdx.x;
  const int w = t >> 6, lane = t & 63;
  const int lrow = lane & 15, lhi = lane >> 4;
  const int m0 = blockIdx.x * 128 + w * 32;
  const int c0 = blockIdx.y * 64;  // within [0,768)
  f32x4 acc[2][4];
#pragma unroll
  for (int qs = 0; qs < 2; ++qs)
#pragma unroll
    for (int nt = 0; nt < 4; ++nt) acc[qs][nt] = f32x4{0.f, 0.f, 0.f, 0.f};

#pragma unroll
  for (int kc = 0; kc < D; kc += 32) {
    f16x8 ah[2], al[2], bw[4];
#pragma unroll
    for (int qs = 0; qs < 2; ++qs) {
      const size_t ao = (size_t)(m0 + qs * 16 + lrow) * D + kc + lhi * 8;
      ah[qs] = *(const f16x8*)(nxh + ao);
      al[qs] = *(const f16x8*)(nxl + ao);
    }
#pragma unroll
    for (int nt = 0; nt < 4; ++nt)
      bw[nt] = *(const f16x8*)(wt + (size_t)(c0 + nt * 16 + lrow) * D + kc +
                               lhi * 8);
#pragma unroll
    for (int qs = 0; qs < 2; ++qs)
#pragma unroll
      for (int nt = 0; nt < 4; ++nt) {
        acc[qs][nt] = mfma_f16(ah[qs], bw[nt], acc[qs][nt]);
        acc[qs][nt] = mfma_f16(al[qs], bw[nt], acc[qs][nt]);
      }
  }

  const int region = blockIdx.y >> 2;  // 0:q 1:k 2:v
  const int cbase = c0 & 255;
  if (region < 2) {
    const float sc = (region == 0) ? QSC2 : 1.0f;
    ushort* dp = (region == 0) ? qfp : kfp;
#pragma unroll
    for (int qs = 0; qs < 2; ++qs)
#pragma unroll
      for (int nt = 0; nt < 4; ++nt)
#pragma unroll
        for (int i = 0; i < 4; ++i) {
          const int row = m0 + qs * 16 + lhi * 4 + i;
          const int col = cbase + nt * 16 + lrow;
          const float val =
              (acc[qs][nt][i] + coord[(size_t)row * D + col]) * sc;
          dp[(size_t)row * D + col] = f2h(val);
        }
  } else {
#pragma unroll
    for (int qs = 0; qs < 2; ++qs)
#pragma unroll
      for (int nt = 0; nt < 4; ++nt)
#pragma unroll
        for (int i = 0; i < 4; ++i) {
          const int row = m0 + qs * 16 + lhi * 4 + i;
          const int col = cbase + nt * 16 + lrow;
          const int bb = row >> 12, n = row & (N - 1);
          vtp[((size_t)bb * D + col) * N + n] = f2h(acc[qs][nt][i]);
        }
  }
}

// ---------------- MFMA flash attention ----------------
// 8 waves/block (512 thr), 16 q-rows/wave (block = 128 rows), KB=32.
// Per-thread state ~128 total regs (o[16]=64 + qfr[8]=32 + rest) so
// __launch_bounds__(512,4) caps at 128 WITHOUT spilling the accumulator
// (round-6 failure mode needed ~256). LDS 73KB -> 2 blocks/CU co-resident
// -> 4 waves/SIMD. SPLIT=4 -> grid 512 = exactly 2 blocks/CU.
__global__ __launch_bounds__(512, 4) void attn_kernel(
    const ushort* __restrict__ qf, const ushort* __restrict__ kf,
    const ushort* __restrict__ vt, ushort* __restrict__ pob,
    float* __restrict__ mlb) {
  __shared__ ushort kbuf[2][8192];
  __shared__ ushort vbuf[2][8192];
  __shared__ ushort ps[8][16 * PSTR];

  const int tid = threadIdx.x;
  const int w = tid >> 6, lane = tid & 63;
  const int lrow = lane & 15, lhi = lane >> 4;
  const int b = blockIdx.y, s = blockIdx.z;
  const int qw = blockIdx.x * 128 + w * 16;
  const int kbeg = s * (N / SPLIT);

  const ushort* qfb = qf + (size_t)b * N * D;
  const ushort* kfb = kf + (size_t)b * N * D;
  const ushort* vtb = vt + (size_t)b * D * N;
  ushort* pog = pob + (size_t)s * BN * D;
  float* mlg = mlb + (size_t)s * BN * 2;

  // Q fragments: 8 d-chunks for this wave's 16 rows
  f16x8 qfr[8];
#pragma unroll
  for (int dc = 0; dc < 8; ++dc)
    qfr[dc] = *(const f16x8*)(qfb + (size_t)(qw + lrow) * D + dc * 32 +
                              lhi * 8);

  f32x4 o[16];
  float m[4], lsum[4];
#pragma unroll
  for (int i = 0; i < 4; ++i) { m[i] = -1e30f; lsum[i] = 0.f; }
#pragma unroll
  for (int nt = 0; nt < 16; ++nt) o[nt] = f32x4{0.f, 0.f, 0.f, 0.f};

  // chunk c = i*8 + w; K dest c*512 covers [g=c*2+(lane>>5)][key=lane&31];
  // V dest c*512 == (c>>2)*2048 + (c&3)*512 covers [sl=c>>2][d=(c&3)*64+lane].
  auto stage = [&](int bi, int k0) {
#pragma unroll
    for (int i = 0; i < 2; ++i) {
      const int c = i * 8 + w;
      gload16(kfb + (size_t)(k0 + (lane & 31)) * D + (c * 2 + (lane >> 5)) * 8,
              &kbuf[bi][c * 512]);
    }
#pragma unroll
    for (int i = 0; i < 2; ++i) {
      const int c = i * 8 + w;
      gload16(vtb + (size_t)((c & 3) * 64 + lane) * N + k0 + (c >> 2) * 8,
              &vbuf[bi][c * 512]);
    }
  };

  stage(0, kbeg);

  for (int t = 0; t < NT; ++t) {
    const int cur = t & 1;
    if (t + 1 < NT) {
      stage(cur ^ 1, kbeg + (t + 1) * KB);
      asm volatile("s_waitcnt vmcnt(4)" ::: "memory");
    } else {
      asm volatile("s_waitcnt vmcnt(0)" ::: "memory");
    }
    __builtin_amdgcn_sched_barrier(0);
    __builtin_amdgcn_s_barrier();
    __builtin_amdgcn_sched_barrier(0);

    // ---- S = Q K^T : 16 rows x 32 keys ----
    f32x4 acc[2];
#pragma unroll
    for (int kt = 0; kt < 2; ++kt) acc[kt] = f32x4{0.f, 0.f, 0.f, 0.f};
    __builtin_amdgcn_s_setprio(1);
#pragma unroll
    for (int dc = 0; dc < 8; ++dc)
#pragma unroll
      for (int kt = 0; kt < 2; ++kt) {
        const f16x8 kv = *(const f16x8*)&kbuf[cur][((dc * 4 + lhi) * 32 +
                                                    kt * 16 + lrow) * 8];
        acc[kt] = mfma_f16(qfr[dc], kv, acc[kt]);
      }
    __builtin_amdgcn_s_setprio(0);

    // ---- online softmax, defer-max ----
    float rm[4];
    bool need = false;
#pragma unroll
    for (int i = 0; i < 4; ++i) {
      float v = fmaxf(acc[0][i], acc[1][i]);
#pragma unroll
      for (int off = 1; off < 16; off <<= 1) v = fmaxf(v, __shfl_xor(v, off));
      rm[i] = v;
      need |= (v > m[i] + THR);
    }
    if (__any(need)) {
#pragma unroll
      for (int i = 0; i < 4; ++i) {
        const float mn = fmaxf(m[i], rm[i]);
        const float f = exp2f(m[i] - mn);
        m[i] = mn;
        lsum[i] *= f;
#pragma unroll
        for (int nt = 0; nt < 16; ++nt) o[nt][i] *= f;
      }
    }
#pragma unroll
    for (int kt = 0; kt < 2; ++kt)
#pragma unroll
      for (int i = 0; i < 4; ++i) {
        const float p = exp2f(acc[kt][i] - m[i]);
        lsum[i] += p;
        ps[w][(lhi * 4 + i) * PSTR + kt * 16 + lrow] = f2h(p);
      }
    asm volatile("s_waitcnt lgkmcnt(0)" ::: "memory");
    __builtin_amdgcn_sched_barrier(0);

    // ---- O += P V (single K=32 step) ----
    const f16x8 pf = *(const f16x8*)&ps[w][lrow * PSTR + lhi * 8];
    __builtin_amdgcn_s_setprio(1);
#pragma unroll
    for (int nt = 0; nt < 16; ++nt) {
      const f16x8 vv =
          *(const f16x8*)&vbuf[cur][lhi * 2048 + (nt * 16 + lrow) * 8];
      o[nt] = mfma_f16(pf, vv, o[nt]);
    }
    __builtin_amdgcn_s_setprio(0);
    __builtin_amdgcn_s_barrier();
    __builtin_amdgcn_sched_barrier(0);
  }

  // ---- epilogue: reduce lsum across the 16 lanes of each row ----
#pragma unroll
  for (int i = 0; i < 4; ++i) {
    float v = lsum[i];
#pragma unroll
    for (int off = 1; off < 16; off <<= 1) v += __shfl_xor(v, off);
    lsum[i] = v;
  }
  float inv[4];
#pragma unroll
  for (int i = 0; i < 4; ++i) inv[i] = 1.0f / lsum[i];
#pragma unroll
  for (int nt = 0; nt < 16; ++nt)
#pragma unroll
    for (int i = 0; i < 4; ++i)
      pog[((size_t)b * N + qw + lhi * 4 + i) * D + nt * 16 + lrow] =
          f2h(o[nt][i] * inv[i]);
  if (lrow == 0) {
#pragma unroll
    for (int i = 0; i < 4; ++i) {
      const size_t r = (size_t)b * N + qw + lhi * 4 + i;
      mlg[r * 2] = m[i];
      mlg[r * 2 + 1] = lsum[i];
    }
  }
}

// ---------------- merge KV-split partials -> f16 hi/lo planes --------------
__global__ __launch_bounds__(256) void merge_kernel(
    const ushort* __restrict__ pob, const float* __restrict__ mlb,
    ushort* __restrict__ aoh, ushort* __restrict__ aol) {
  const int t = threadIdx.x;
  const int row = blockIdx.x * 8 + (t >> 5);
  const int d0 = (t & 31) * 8;
  float mv[SPLIT], lv[SPLIT];
  float mm = -1e30f;
#pragma unroll
  for (int s = 0; s < SPLIT; ++s) {
    mv[s] = mlb[(size_t)s * BN * 2 + row * 2];
    lv[s] = mlb[(size_t)s * BN * 2 + row * 2 + 1];
    mm = fmaxf(mm, mv[s]);
  }
  float wsum = 0.f, a[SPLIT];
#pragma unroll
  for (int s = 0; s < SPLIT; ++s) {
    a[s] = exp2f(mv[s] - mm) * lv[s];
    wsum += a[s];
  }
  const float invw = 1.0f / wsum;
  const size_t off = (size_t)row * D + d0;
  float r[8] = {};
#pragma unroll
  for (int s = 0; s < SPLIT; ++s) {
    const f16x8 p = *(const f16x8*)(pob + (size_t)s * BN * D + off);
    const float c = a[s] * invw;
#pragma unroll
    for (int j = 0; j < 8; ++j) r[j] += c * (float)p[j];
  }
  f16x8 rh, rl;
#pragma unroll
  for (int j = 0; j < 8; ++j) {
    rh[j] = (_Float16)r[j];
    rl[j] = (_Float16)(r[j] - (float)rh[j]);
  }
  *(f16x8*)(aoh + off) = rh;
  *(f16x8*)(aol + off) = rl;
}

// ---------------- output projection via MFMA (no LDS) ----------------
__global__ __launch_bounds__(256, 4) void proj_kernel(
    const ushort* __restrict__ aoh, const ushort* __restrict__ aol,
    const ushort* __restrict__ wot, const float* __restrict__ bias,
    float* __restrict__ out) {
  const int t = threadIdx.x;
  const int w = t >> 6, lane = t & 63;
  const int lrow = lane & 15, lhi = lane >> 4;
  const int m0 = blockIdx.x * 128 + w * 32;
  const int c0 = blockIdx.y * 64;
  f32x4 acc[2][4];
#pragma unroll
  for (int qs = 0; qs < 2; ++qs)
#pragma unroll
    for (int nt = 0; nt < 4; ++nt) acc[qs][nt] = f32x4{0.f, 0.f, 0.f, 0.f};

#pragma unroll
  for (int kc = 0; kc < D; kc += 32) {
    f16x8 ah[2], al[2], bw[4];
#pragma unroll
    for (int qs = 0; qs < 2; ++qs) {
      const size_t ao = (size_t)(m0 + qs * 16 + lrow) * D + kc + lhi * 8;
      ah[qs] = *(const f16x8*)(aoh + ao);
      al[qs] = *(const f16x8*)(aol + ao);
    }
#pragma unroll
    for (int nt = 0; nt < 4; ++nt)
      bw[nt] = *(const f16x8*)(wot + (size_t)(c0 + nt * 16 + lrow) * D + kc +
                               lhi * 8);
#pragma unroll
    for (int qs = 0; qs < 2; ++qs)
#pragma unroll
      for (int nt = 0; nt < 4; ++nt) {
        acc[qs][nt] = mfma_f16(ah[qs], bw[nt], acc[qs][nt]);
        acc[qs][nt] = mfma_f16(al[qs], bw[nt], acc[qs][nt]);
      }
  }
#pragma unroll
  for (int qs = 0; qs < 2; ++qs)
#pragma unroll
    for (int nt = 0; nt < 4; ++nt)
#pragma unroll
      for (int i = 0; i < 4; ++i) {
        const int row = m0 + qs * 16 + lhi * 4 + i;
        const int col = c0 + nt * 16 + lrow;
        out[(size_t)row * D + col] = acc[qs][nt][i] + bias[col];
      }
}

extern "C" void kernel_launch(void* const* d_in, const int* in_sizes, int n_in,
                              void* d_out, int out_size, void* d_ws, size_t ws_size,
                              hipStream_t stream) {
  const float* x = (const float*)d_in[0];
  const float* coord = (const float*)d_in[1];
  const float* ln_g = (const float*)d_in[2];
  const float* ln_b = (const float*)d_in[3];
  const float* w_qkv = (const float*)d_in[4];
  const float* w_out = (const float*)d_in[5];
  const float* b_out = (const float*)d_in[6];
  float* out = (float*)d_out;

  const size_t P = (size_t)BN * D;

  ushort* qfp = (ushort*)d_ws;
  ushort* kfp = qfp + P;
  ushort* vtp = kfp + P;
  ushort* pob = vtp + P;                      // SPLIT partial-O planes
  float* mlb = (float*)(pob + (size_t)SPLIT * P);
  ushort* wt = (ushort*)(mlb + (size_t)SPLIT * BN * 2);
  ushort* wot = wt + 768 * 256;
  // aliases (liveness-disjoint):
  ushort* nxh = pob;       // written by ln, consumed by qkv, dead before attn
  ushort* nxl = pob + P;
  ushort* aoh = qfp;       // written by merge after q/k are dead
  ushort* aol = kfp;

  hipLaunchKernelGGL(ln_kernel, dim3(BN), dim3(256), 0, stream,
                     x, ln_g, ln_b, nxh, nxl);
  hipLaunchKernelGGL(castw_kernel, dim3(1024), dim3(256), 0, stream,
                     w_qkv, w_out, wt, wot);
  hipLaunchKernelGGL(qkv_kernel, dim3(BN / 128, 12), dim3(256), 0, stream,
                     nxh, nxl, wt, coord, qfp, kfp, vtp);
  hipLaunchKernelGGL(attn_kernel, dim3(N / 128, B, SPLIT), dim3(512), 0,
                     stream, qfp, kfp, vtp, pob, mlb);
  hipLaunchKernelGGL(merge_kernel, dim3(BN / 8), dim3(256), 0, stream,
                     pob, mlb, aoh, aol);
  hipLaunchKernelGGL(proj_kernel, dim3(BN / 128, 4), dim3(256), 0, stream,
                     aoh, aol, wot, b_out, out);
}

// Round 12
// 239.076 us; speedup vs baseline: 4.9940x; 1.1282x over previous
//
#include <hip/hip_runtime.h>
#include <hip/hip_fp16.h>
#include <math.h>

constexpr int B = 4, N = 4096, D = 256;
constexpr int BN = B * N;
constexpr float EPS = 1e-5f;
// softmax scale (D^-0.5 = 1/16) * log2(e), folded into q at f16-cast time
constexpr float QSC2 = 0.0625f * 1.44269504088896340736f;

constexpr int SPLIT = 4;     // KV splits -> grid 256 blocks (1/CU)
constexpr int KVB = 64;      // keys per attn tile
constexpr int NTK = (N / SPLIT) / KVB;  // 16 tiles
constexpr float THR = 8.0f;  // defer-max threshold (base-2)

typedef __attribute__((ext_vector_type(8))) _Float16 f16x8;
typedef __attribute__((ext_vector_type(2))) __fp16 fp16x2;
typedef __attribute__((ext_vector_type(4))) float f32x4;
typedef __attribute__((ext_vector_type(16))) float f32x16;

__device__ inline f32x4 mfma_f16(f16x8 a, f16x8 b, f32x4 c) {
  return __builtin_amdgcn_mfma_f32_16x16x32_f16(a, b, c, 0, 0, 0);
}
__device__ inline f32x16 mfma32(f16x8 a, f16x8 b, f32x16 c) {
  return __builtin_amdgcn_mfma_f32_32x32x16_f16(a, b, c, 0, 0, 0);
}
__device__ inline ushort f2h(float x) {
  __half h = __float2half(x);
  return *(ushort*)&h;
}
__device__ inline float h2f(ushort u) {
  __half h;
  *(ushort*)&h = u;
  return __half2float(h);
}
__device__ inline unsigned pkh(float a, float b) {
  fp16x2 r = __builtin_amdgcn_cvt_pkrtz(a, b);
  return *(unsigned*)&r;
}
// async global->LDS, 16B per lane; lds dest = uniform base + lane*16 (HW rule)
__device__ inline void gload16(const ushort* g, ushort* l) {
  __builtin_amdgcn_global_load_lds(
      (const __attribute__((address_space(1))) void*)g,
      (__attribute__((address_space(3))) void*)l, 16, 0, 0);
}

// ---------------- LayerNorm -> normalized x as f16 hi/lo planes ------------
__global__ __launch_bounds__(256) void ln_kernel(
    const float* __restrict__ x, const float* __restrict__ g,
    const float* __restrict__ bta, ushort* __restrict__ nxh,
    ushort* __restrict__ nxl) {
  const int row = blockIdx.x;
  const int t = threadIdx.x;
  const float v = x[(size_t)row * D + t];
  float s = v, ss = v * v;
#pragma unroll
  for (int o = 32; o > 0; o >>= 1) {
    s += __shfl_down(s, o);
    ss += __shfl_down(ss, o);
  }
  __shared__ float red[8];
  if ((t & 63) == 0) {
    red[t >> 6] = s;
    red[(t >> 6) + 4] = ss;
  }
  __syncthreads();
  s = red[0] + red[1] + red[2] + red[3];
  ss = red[4] + red[5] + red[6] + red[7];
  const float mu = s * (1.0f / D);
  const float var = ss * (1.0f / D) - mu * mu;
  const float rsig = rsqrtf(var + EPS);
  const float nx = (v - mu) * rsig * g[t] + bta[t];
  const ushort h = f2h(nx);
  nxh[(size_t)row * D + t] = h;
  nxl[(size_t)row * D + t] = f2h(nx - h2f(h));
}

// ------------- cast + transpose weights to f16 (wt[768][256], wot[256][256])
__global__ __launch_bounds__(256) void castw_kernel(
    const float* __restrict__ w_qkv, const float* __restrict__ w_out,
    ushort* __restrict__ wt, ushort* __restrict__ wot) {
  const int id = blockIdx.x * 256 + threadIdx.x;
  if (id < 768 * 256) {
    const int n = id >> 8, k = id & 255;
    wt[id] = f2h(w_qkv[(size_t)k * 768 + n]);
  } else {
    const int j = id - 768 * 256;
    const int n = j >> 8, k = j & 255;
    wot[j] = f2h(w_out[(size_t)k * 256 + n]);
  }
}

// ---------------- QKV GEMM via MFMA (no LDS; weights L2-hot) ---------------
__global__ __launch_bounds__(256, 4) void qkv_kernel(
    const ushort* __restrict__ nxh, const ushort* __restrict__ nxl,
    const ushort* __restrict__ wt, const float* __restrict__ coord,
    ushort* __restrict__ qfp, ushort* __restrict__ kfp,
    ushort* __restrict__ vtp) {
  const int t = threadIdx.x;
  const int w = t >> 6, lane = t & 63;
  const int lrow = lane & 15, lhi = lane >> 4;
  const int m0 = blockIdx.x * 128 + w * 32;
  const int c0 = blockIdx.y * 64;  // within [0,768)
  f32x4 acc[2][4];
#pragma unroll
  for (int qs = 0; qs < 2; ++qs)
#pragma unroll
    for (int nt = 0; nt < 4; ++nt) acc[qs][nt] = f32x4{0.f, 0.f, 0.f, 0.f};

#pragma unroll
  for (int kc = 0; kc < D; kc += 32) {
    f16x8 ah[2], al[2], bw[4];
#pragma unroll
    for (int qs = 0; qs < 2; ++qs) {
      const size_t ao = (size_t)(m0 + qs * 16 + lrow) * D + kc + lhi * 8;
      ah[qs] = *(const f16x8*)(nxh + ao);
      al[qs] = *(const f16x8*)(nxl + ao);
    }
#pragma unroll
    for (int nt = 0; nt < 4; ++nt)
      bw[nt] = *(const f16x8*)(wt + (size_t)(c0 + nt * 16 + lrow) * D + kc +
                               lhi * 8);
#pragma unroll
    for (int qs = 0; qs < 2; ++qs)
#pragma unroll
      for (int nt = 0; nt < 4; ++nt) {
        acc[qs][nt] = mfma_f16(ah[qs], bw[nt], acc[qs][nt]);
        acc[qs][nt] = mfma_f16(al[qs], bw[nt], acc[qs][nt]);
      }
  }

  const int region = blockIdx.y >> 2;  // 0:q 1:k 2:v
  const int cbase = c0 & 255;
  if (region < 2) {
    const float sc = (region == 0) ? QSC2 : 1.0f;
    ushort* dp = (region == 0) ? qfp : kfp;
#pragma unroll
    for (int qs = 0; qs < 2; ++qs)
#pragma unroll
      for (int nt = 0; nt < 4; ++nt)
#pragma unroll
        for (int i = 0; i < 4; ++i) {
          const int row = m0 + qs * 16 + lhi * 4 + i;
          const int col = cbase + nt * 16 + lrow;
          const float val =
              (acc[qs][nt][i] + coord[(size_t)row * D + col]) * sc;
          dp[(size_t)row * D + col] = f2h(val);
        }
  } else {
#pragma unroll
    for (int qs = 0; qs < 2; ++qs)
#pragma unroll
      for (int nt = 0; nt < 4; ++nt)
#pragma unroll
        for (int i = 0; i < 4; ++i) {
          const int row = m0 + qs * 16 + lhi * 4 + i;
          const int col = cbase + nt * 16 + lrow;
          const int bb = row >> 12, n = row & (N - 1);
          vtp[((size_t)bb * D + col) * N + n] = f2h(acc[qs][nt][i]);
        }
  }
}

// ---------------- MFMA flash attention (32x32 swapped-operand) -------------
// 8 warps x 32 q-rows (block = 256 rows), KVB=64 keys/tile, SPLIT=4.
// S^T = mfma32(K, Q): lane holds col=qrow(lane&31); p[reg] = P[q][key] with
// key = (reg&3) + 8*(reg>>2) + 4*h. ALL cross-lane ops use __shfl_xor(.,32)
// (rounds 10/11 lost to v_permlane32_swap semantics; shfl is verified).
// K LDS [64 key][256 d], V^T LDS [256 d][64 key], granule-XOR-swizzled via
// pre-swizzled global_load_lds SOURCE. O^T = 8 f32x16 tiles (128 f32).
__global__ __launch_bounds__(512, 2) void attn_kernel(
    const ushort* __restrict__ qf, const ushort* __restrict__ kf,
    const ushort* __restrict__ vt, ushort* __restrict__ pob,
    float* __restrict__ mlb) {
  __shared__ ushort kbuf[2][16384];  // 32KB each
  __shared__ ushort vbuf[2][16384];  // 32KB each

  const int tid = threadIdx.x;
  const int w = tid >> 6, lane = tid & 63;
  const int q = lane & 31, h = lane >> 5;
  const int b = blockIdx.y, s = blockIdx.z;
  const int qw = blockIdx.x * 256 + w * 32;
  const int kbeg = s * (N / SPLIT);

  const ushort* qrow = qf + ((size_t)b * N + qw + q) * D;
  const ushort* kfb = kf + (size_t)b * N * D;
  const ushort* vtb = vt + (size_t)b * D * N;
  ushort* pog = pob + (size_t)s * BN * D;
  float* mlg = mlb + (size_t)s * BN * 2;

  // persistent Q chunks 0..7 (d 0..127); chunks 8..15 streamed per tile
  f16x8 qfr[8];
#pragma unroll
  for (int c = 0; c < 8; ++c)
    qfr[c] = *(const f16x8*)(qrow + c * 16 + h * 8);

  f32x16 o[8];
#pragma unroll
  for (int dt = 0; dt < 8; ++dt)
#pragma unroll
    for (int r = 0; r < 16; ++r) o[dt][r] = 0.f;
  float m = -1e30f, lsum = 0.f;

  // stage one 64-key K+V tile; 8 granule-loads per thread.
  // K: granule g -> key=g>>5, slot=g&31, content = global d-granule slot^(key&7)
  // V: granule g -> d=g>>3, sg=g&7, content = global key-granule sg^(d&7)
  auto stage = [&](int bi, int k0) {
#pragma unroll
    for (int i = 0; i < 4; ++i) {
      const int g = i * 512 + tid;
      const int key = g >> 5, slot = g & 31;
      gload16(kfb + (size_t)(k0 + key) * D + ((slot ^ (key & 7)) * 8),
              &kbuf[bi][g * 8]);
    }
#pragma unroll
    for (int i = 0; i < 4; ++i) {
      const int g = i * 512 + tid;
      const int d = g >> 3, sg = g & 7;
      gload16(vtb + (size_t)d * N + k0 + ((sg ^ (d & 7)) * 8),
              &vbuf[bi][g * 8]);
    }
  };

  stage(0, kbeg);

  for (int t = 0; t < NTK; ++t) {
    const int cur = t & 1;
    // stream Q chunks 8..15 (issued BEFORE next-tile stage so waits on these
    // never drain the prefetch)
    f16x8 qs[8];
#pragma unroll
    for (int c = 0; c < 8; ++c)
      qs[c] = *(const f16x8*)(qrow + (8 + c) * 16 + h * 8);
    if (t + 1 < NTK) {
      stage(cur ^ 1, kbeg + (t + 1) * KVB);
      asm volatile("s_waitcnt vmcnt(16)" ::: "memory");  // drain tile-t stage
    } else {
      asm volatile("s_waitcnt vmcnt(8)" ::: "memory");   // qs still in flight
    }
    __builtin_amdgcn_sched_barrier(0);
    __builtin_amdgcn_s_barrier();
    __builtin_amdgcn_sched_barrier(0);

    // ---- S^T = K Q : two 32x32 C-tiles (keys 0..31, 32..63) ----
    f32x16 p0, p1;
#pragma unroll
    for (int r = 0; r < 16; ++r) { p0[r] = 0.f; p1[r] = 0.f; }
    const int ksw = (q & 7);
    __builtin_amdgcn_s_setprio(1);
#pragma unroll
    for (int c = 0; c < 16; ++c) {
      const f16x8 qv = (c < 8) ? qfr[c] : qs[c - 8];
      const f16x8 ka = *(const f16x8*)&kbuf[cur][q * 256 +
                                                 (((c * 2 + h) ^ ksw) * 8)];
      const f16x8 kb_ = *(const f16x8*)&kbuf[cur][(32 + q) * 256 +
                                                  (((c * 2 + h) ^ ksw) * 8)];
      p0 = mfma32(ka, qv, p0);
      p1 = mfma32(kb_, qv, p1);
    }
    __builtin_amdgcn_s_setprio(0);

    // ---- softmax: in-lane tree + cross-half shfl ----
    float tm[8];
#pragma unroll
    for (int j = 0; j < 8; ++j)
      tm[j] = fmaxf(fmaxf(p0[2 * j], p0[2 * j + 1]),
                    fmaxf(p1[2 * j], p1[2 * j + 1]));
    float pmax = fmaxf(fmaxf(fmaxf(tm[0], tm[1]), fmaxf(tm[2], tm[3])),
                       fmaxf(fmaxf(tm[4], tm[5]), fmaxf(tm[6], tm[7])));
    const float pm = fmaxf(pmax, __shfl_xor(pmax, 32));
    const bool need = pm > m + THR;
    if (__any(need)) {
      const float mn = fmaxf(m, pm);
      const float f = exp2f(m - mn);
      m = mn;
      lsum *= f;
#pragma unroll
      for (int dt = 0; dt < 8; ++dt) o[dt] *= f;
    }
#pragma unroll
    for (int r = 0; r < 16; ++r) {
      p0[r] = exp2f(p0[r] - m);
      lsum += p0[r];
      p1[r] = exp2f(p1[r] - m);
      lsum += p1[r];
    }

    // ---- pack P -> 4 PV B-frags (16 keys each) via cvt_pkrtz + shfl ----
    // lane(q,h) owns packed words: x=keys(4h,4h+1) z=(4h+2,4h+3)
    // y=(8+4h,9+4h) wv=(10+4h,11+4h). B-frag needs word_j = keys(h*8+2j, +1):
    // word0 = h? partner-y : x ; word1 = h? partner-wv : z ;
    // word2 = h? y : partner-x ; word3 = h? wv : partner-z.
    f16x8 pf[4];
#pragma unroll
    for (int kk = 0; kk < 4; ++kk) {
      const int sub = (kk & 1) * 8;
      unsigned x, z, y, wv;
      if (kk < 2) {
        x = pkh(p0[sub + 0], p0[sub + 1]);
        z = pkh(p0[sub + 2], p0[sub + 3]);
        y = pkh(p0[sub + 4], p0[sub + 5]);
        wv = pkh(p0[sub + 6], p0[sub + 7]);
      } else {
        x = pkh(p1[sub + 0], p1[sub + 1]);
        z = pkh(p1[sub + 2], p1[sub + 3]);
        y = pkh(p1[sub + 4], p1[sub + 5]);
        wv = pkh(p1[sub + 6], p1[sub + 7]);
      }
      const unsigned xs = __shfl_xor(x, 32);
      const unsigned zs = __shfl_xor(z, 32);
      const unsigned ys = __shfl_xor(y, 32);
      const unsigned ws = __shfl_xor(wv, 32);
      union { f16x8 v; unsigned u[4]; } pu;
      pu.u[0] = h ? ys : x;
      pu.u[1] = h ? ws : z;
      pu.u[2] = h ? y : xs;
      pu.u[3] = h ? wv : zs;
      pf[kk] = pu.v;
    }

    // ---- O^T += V^T P^T : 8 d-tiles x 4 key-chunks ----
    __builtin_amdgcn_s_setprio(1);
#pragma unroll
    for (int dt = 0; dt < 8; ++dt) {
      const int d = dt * 32 + q;
      const int dsw = d & 7;
#pragma unroll
      for (int kk = 0; kk < 4; ++kk) {
        const f16x8 vf = *(const f16x8*)&vbuf[cur][d * 64 +
                                                   (((kk * 2 + h) ^ dsw) * 8)];
        o[dt] = mfma32(vf, pf[kk], o[dt]);
      }
    }
    __builtin_amdgcn_s_setprio(0);
    __builtin_amdgcn_s_barrier();
    __builtin_amdgcn_sched_barrier(0);
  }

  // ---- epilogue: cross-half lsum, normalize, write O (row = qw+q) ----
  const float lt = lsum + __shfl_xor(lsum, 32);
  const float inv = 1.0f / lt;
  ushort* orow = pog + ((size_t)b * N + qw + q) * D;
#pragma unroll
  for (int dt = 0; dt < 8; ++dt)
#pragma unroll
    for (int r4 = 0; r4 < 4; ++r4) {
      const unsigned u0 =
          pkh(o[dt][r4 * 4 + 0] * inv, o[dt][r4 * 4 + 1] * inv);
      const unsigned u1 =
          pkh(o[dt][r4 * 4 + 2] * inv, o[dt][r4 * 4 + 3] * inv);
      uint2 val;
      val.x = u0;
      val.y = u1;
      *(uint2*)(orow + dt * 32 + r4 * 8 + h * 4) = val;
    }
  if (h == 0) {
    const size_t r = (size_t)b * N + qw + q;
    mlg[r * 2] = m;
    mlg[r * 2 + 1] = lt;
  }
}

// ---------------- merge KV-split partials -> f16 hi/lo planes --------------
__global__ __launch_bounds__(256) void merge_kernel(
    const ushort* __restrict__ pob, const float* __restrict__ mlb,
    ushort* __restrict__ aoh, ushort* __restrict__ aol) {
  const int t = threadIdx.x;
  const int row = blockIdx.x * 8 + (t >> 5);
  const int d0 = (t & 31) * 8;
  float mv[SPLIT], lv[SPLIT];
  float mm = -1e30f;
#pragma unroll
  for (int s = 0; s < SPLIT; ++s) {
    mv[s] = mlb[(size_t)s * BN * 2 + row * 2];
    lv[s] = mlb[(size_t)s * BN * 2 + row * 2 + 1];
    mm = fmaxf(mm, mv[s]);
  }
  float wsum = 0.f, a[SPLIT];
#pragma unroll
  for (int s = 0; s < SPLIT; ++s) {
    a[s] = exp2f(mv[s] - mm) * lv[s];
    wsum += a[s];
  }
  const float invw = 1.0f / wsum;
  const size_t off = (size_t)row * D + d0;
  float r[8] = {};
#pragma unroll
  for (int s = 0; s < SPLIT; ++s) {
    const f16x8 p = *(const f16x8*)(pob + (size_t)s * BN * D + off);
    const float c = a[s] * invw;
#pragma unroll
    for (int j = 0; j < 8; ++j) r[j] += c * (float)p[j];
  }
  f16x8 rh, rl;
#pragma unroll
  for (int j = 0; j < 8; ++j) {
    rh[j] = (_Float16)r[j];
    rl[j] = (_Float16)(r[j] - (float)rh[j]);
  }
  *(f16x8*)(aoh + off) = rh;
  *(f16x8*)(aol + off) = rl;
}

// ---------------- output projection via MFMA (no LDS) ----------------
__global__ __launch_bounds__(256, 4) void proj_kernel(
    const ushort* __restrict__ aoh, const ushort* __restrict__ aol,
    const ushort* __restrict__ wot, const float* __restrict__ bias,
    float* __restrict__ out) {
  const int t = threadIdx.x;
  const int w = t >> 6, lane = t & 63;
  const int lrow = lane & 15, lhi = lane >> 4;
  const int m0 = blockIdx.x * 128 + w * 32;
  const int c0 = blockIdx.y * 64;
  f32x4 acc[2][4];
#pragma unroll
  for (int qs = 0; qs < 2; ++qs)
#pragma unroll
    for (int nt = 0; nt < 4; ++nt) acc[qs][nt] = f32x4{0.f, 0.f, 0.f, 0.f};

#pragma unroll
  for (int kc = 0; kc < D; kc += 32) {
    f16x8 ah[2], al[2], bw[4];
#pragma unroll
    for (int qs = 0; qs < 2; ++qs) {
      const size_t ao = (size_t)(m0 + qs * 16 + lrow) * D + kc + lhi * 8;
      ah[qs] = *(const f16x8*)(aoh + ao);
      al[qs] = *(const f16x8*)(aol + ao);
    }
#pragma unroll
    for (int nt = 0; nt < 4; ++nt)
      bw[nt] = *(const f16x8*)(wot + (size_t)(c0 + nt * 16 + lrow) * D + kc +
                               lhi * 8);
#pragma unroll
    for (int qs = 0; qs < 2; ++qs)
#pragma unroll
      for (int nt = 0; nt < 4; ++nt) {
        acc[qs][nt] = mfma_f16(ah[qs], bw[nt], acc[qs][nt]);
        acc[qs][nt] = mfma_f16(al[qs], bw[nt], acc[qs][nt]);
      }
  }
#pragma unroll
  for (int qs = 0; qs < 2; ++qs)
#pragma unroll
    for (int nt = 0; nt < 4; ++nt)
#pragma unroll
      for (int i = 0; i < 4; ++i) {
        const int row = m0 + qs * 16 + lhi * 4 + i;
        const int col = c0 + nt * 16 + lrow;
        out[(size_t)row * D + col] = acc[qs][nt][i] + bias[col];
      }
}

extern "C" void kernel_launch(void* const* d_in, const int* in_sizes, int n_in,
                              void* d_out, int out_size, void* d_ws, size_t ws_size,
                              hipStream_t stream) {
  const float* x = (const float*)d_in[0];
  const float* coord = (const float*)d_in[1];
  const float* ln_g = (const float*)d_in[2];
  const float* ln_b = (const float*)d_in[3];
  const float* w_qkv = (const float*)d_in[4];
  const float* w_out = (const float*)d_in[5];
  const float* b_out = (const float*)d_in[6];
  float* out = (float*)d_out;

  const size_t P = (size_t)BN * D;

  ushort* qfp = (ushort*)d_ws;
  ushort* kfp = qfp + P;
  ushort* vtp = kfp + P;
  ushort* pob = vtp + P;                      // SPLIT partial-O planes
  float* mlb = (float*)(pob + (size_t)SPLIT * P);
  ushort* wt = (ushort*)(mlb + (size_t)SPLIT * BN * 2);
  ushort* wot = wt + 768 * 256;
  // aliases (liveness-disjoint):
  ushort* nxh = pob;       // written by ln, consumed by qkv, dead before attn
  ushort* nxl = pob + P;
  ushort* aoh = qfp;       // written by merge after q/k are dead
  ushort* aol = kfp;

  hipLaunchKernelGGL(ln_kernel, dim3(BN), dim3(256), 0, stream,
                     x, ln_g, ln_b, nxh, nxl);
  hipLaunchKernelGGL(castw_kernel, dim3(1024), dim3(256), 0, stream,
                     w_qkv, w_out, wt, wot);
  hipLaunchKernelGGL(qkv_kernel, dim3(BN / 128, 12), dim3(256), 0, stream,
                     nxh, nxl, wt, coord, qfp, kfp, vtp);
  hipLaunchKernelGGL(attn_kernel, dim3(N / 256, B, SPLIT), dim3(512), 0,
                     stream, qfp, kfp, vtp, pob, mlb);
  hipLaunchKernelGGL(merge_kernel, dim3(BN / 8), dim3(256), 0, stream,
                     pob, mlb, aoh, aol);
  hipLaunchKernelGGL(proj_kernel, dim3(BN / 128, 4), dim3(256), 0, stream,
                     aoh, aol, wot, b_out, out);
}

// Round 13
// 210.523 us; speedup vs baseline: 5.6714x; 1.1356x over previous
//
#include <hip/hip_runtime.h>
#include <hip/hip_fp16.h>
#include <math.h>

constexpr int B = 4, N = 4096, D = 256;
constexpr int BN = B * N;
constexpr float EPS = 1e-5f;
// softmax scale (D^-0.5 = 1/16) * log2(e), folded into q at f16-cast time
constexpr float QSC2 = 0.0625f * 1.44269504088896340736f;

constexpr int SPLIT = 4;     // KV splits -> grid 256 blocks (1/CU)
constexpr int KVB = 32;      // keys per attn tile
constexpr int NTK = (N / SPLIT) / KVB;  // 32 tiles
constexpr float THR = 8.0f;  // defer-max threshold (base-2)

typedef __attribute__((ext_vector_type(8))) _Float16 f16x8;
typedef __attribute__((ext_vector_type(2))) __fp16 fp16x2;
typedef __attribute__((ext_vector_type(4))) float f32x4;
typedef __attribute__((ext_vector_type(16))) float f32x16;

__device__ inline f32x4 mfma_f16(f16x8 a, f16x8 b, f32x4 c) {
  return __builtin_amdgcn_mfma_f32_16x16x32_f16(a, b, c, 0, 0, 0);
}
__device__ inline f32x16 mfma32(f16x8 a, f16x8 b, f32x16 c) {
  return __builtin_amdgcn_mfma_f32_32x32x16_f16(a, b, c, 0, 0, 0);
}
__device__ inline ushort f2h(float x) {
  __half h = __float2half(x);
  return *(ushort*)&h;
}
__device__ inline float h2f(ushort u) {
  __half h;
  *(ushort*)&h = u;
  return __half2float(h);
}
__device__ inline unsigned pkh(float a, float b) {
  fp16x2 r = __builtin_amdgcn_cvt_pkrtz(a, b);
  return *(unsigned*)&r;
}
// async global->LDS, 16B per lane; lds dest = uniform base + lane*16 (HW rule)
__device__ inline void gload16(const ushort* g, ushort* l) {
  __builtin_amdgcn_global_load_lds(
      (const __attribute__((address_space(1))) void*)g,
      (__attribute__((address_space(3))) void*)l, 16, 0, 0);
}

// ---------------- LayerNorm -> normalized x as f16 hi/lo planes ------------
__global__ __launch_bounds__(256) void ln_kernel(
    const float* __restrict__ x, const float* __restrict__ g,
    const float* __restrict__ bta, ushort* __restrict__ nxh,
    ushort* __restrict__ nxl) {
  const int row = blockIdx.x;
  const int t = threadIdx.x;
  const float v = x[(size_t)row * D + t];
  float s = v, ss = v * v;
#pragma unroll
  for (int o = 32; o > 0; o >>= 1) {
    s += __shfl_down(s, o);
    ss += __shfl_down(ss, o);
  }
  __shared__ float red[8];
  if ((t & 63) == 0) {
    red[t >> 6] = s;
    red[(t >> 6) + 4] = ss;
  }
  __syncthreads();
  s = red[0] + red[1] + red[2] + red[3];
  ss = red[4] + red[5] + red[6] + red[7];
  const float mu = s * (1.0f / D);
  const float var = ss * (1.0f / D) - mu * mu;
  const float rsig = rsqrtf(var + EPS);
  const float nx = (v - mu) * rsig * g[t] + bta[t];
  const ushort h = f2h(nx);
  nxh[(size_t)row * D + t] = h;
  nxl[(size_t)row * D + t] = f2h(nx - h2f(h));
}

// ------------- cast + transpose weights to f16 (wt[768][256], wot[256][256])
__global__ __launch_bounds__(256) void castw_kernel(
    const float* __restrict__ w_qkv, const float* __restrict__ w_out,
    ushort* __restrict__ wt, ushort* __restrict__ wot) {
  const int id = blockIdx.x * 256 + threadIdx.x;
  if (id < 768 * 256) {
    const int n = id >> 8, k = id & 255;
    wt[id] = f2h(w_qkv[(size_t)k * 768 + n]);
  } else {
    const int j = id - 768 * 256;
    const int n = j >> 8, k = j & 255;
    wot[j] = f2h(w_out[(size_t)k * 256 + n]);
  }
}

// ---------------- QKV GEMM via MFMA (no LDS; weights L2-hot) ---------------
__global__ __launch_bounds__(256, 4) void qkv_kernel(
    const ushort* __restrict__ nxh, const ushort* __restrict__ nxl,
    const ushort* __restrict__ wt, const float* __restrict__ coord,
    ushort* __restrict__ qfp, ushort* __restrict__ kfp,
    ushort* __restrict__ vtp) {
  const int t = threadIdx.x;
  const int w = t >> 6, lane = t & 63;
  const int lrow = lane & 15, lhi = lane >> 4;
  const int m0 = blockIdx.x * 128 + w * 32;
  const int c0 = blockIdx.y * 64;  // within [0,768)
  f32x4 acc[2][4];
#pragma unroll
  for (int qs = 0; qs < 2; ++qs)
#pragma unroll
    for (int nt = 0; nt < 4; ++nt) acc[qs][nt] = f32x4{0.f, 0.f, 0.f, 0.f};

#pragma unroll
  for (int kc = 0; kc < D; kc += 32) {
    f16x8 ah[2], al[2], bw[4];
#pragma unroll
    for (int qs = 0; qs < 2; ++qs) {
      const size_t ao = (size_t)(m0 + qs * 16 + lrow) * D + kc + lhi * 8;
      ah[qs] = *(const f16x8*)(nxh + ao);
      al[qs] = *(const f16x8*)(nxl + ao);
    }
#pragma unroll
    for (int nt = 0; nt < 4; ++nt)
      bw[nt] = *(const f16x8*)(wt + (size_t)(c0 + nt * 16 + lrow) * D + kc +
                               lhi * 8);
#pragma unroll
    for (int qs = 0; qs < 2; ++qs)
#pragma unroll
      for (int nt = 0; nt < 4; ++nt) {
        acc[qs][nt] = mfma_f16(ah[qs], bw[nt], acc[qs][nt]);
        acc[qs][nt] = mfma_f16(al[qs], bw[nt], acc[qs][nt]);
      }
  }

  const int region = blockIdx.y >> 2;  // 0:q 1:k 2:v
  const int cbase = c0 & 255;
  if (region < 2) {
    const float sc = (region == 0) ? QSC2 : 1.0f;
    ushort* dp = (region == 0) ? qfp : kfp;
#pragma unroll
    for (int qs = 0; qs < 2; ++qs)
#pragma unroll
      for (int nt = 0; nt < 4; ++nt)
#pragma unroll
        for (int i = 0; i < 4; ++i) {
          const int row = m0 + qs * 16 + lhi * 4 + i;
          const int col = cbase + nt * 16 + lrow;
          const float val =
              (acc[qs][nt][i] + coord[(size_t)row * D + col]) * sc;
          dp[(size_t)row * D + col] = f2h(val);
        }
  } else {
#pragma unroll
    for (int qs = 0; qs < 2; ++qs)
#pragma unroll
      for (int nt = 0; nt < 4; ++nt)
#pragma unroll
        for (int i = 0; i < 4; ++i) {
          const int row = m0 + qs * 16 + lhi * 4 + i;
          const int col = cbase + nt * 16 + lrow;
          const int bb = row >> 12, n = row & (N - 1);
          vtp[((size_t)bb * D + col) * N + n] = f2h(acc[qs][nt][i]);
        }
  }
}

// ---------------- MFMA flash attention (32x32 swapped-operand) -------------
// 8 warps x 32 q-rows (block = 256 rows), KVB=32 keys/tile, SPLIT=4.
// TRIPLE-buffered K/V staging (16KB each x6 = 96KB LDS) allows exactly ONE
// s_barrier per tile: stage(t+1) targets buf[(t+1)%3], never colliding with
// buf[t%3] (current reads) or buf[(t-1)%3] (slowest wave's reads). Waves
// drift up to a full tile apart, so one wave's softmax VALU overlaps
// another's QK/PV MFMA on the same SIMD (round-12's 2-barrier phase lock
// kept MFMA+VALU at 18%+19%).
// S^T = mfma32(K, Q): lane holds col=qrow(lane&31); p[reg] = P[q][key] with
// key = (reg&3) + 8*(reg>>2) + 4*h. QK split into pa+pb partials (2 MFMA
// chains). Cross-lane via __shfl_xor(.,32) only.
__global__ __launch_bounds__(512, 2) void attn_kernel(
    const ushort* __restrict__ qf, const ushort* __restrict__ kf,
    const ushort* __restrict__ vt, ushort* __restrict__ pob,
    float* __restrict__ mlb) {
  __shared__ ushort kbuf[3][8192];  // [key 0..31][slot 0..31 granules] 16KB
  __shared__ ushort vbuf[3][8192];  // [d 0..255][sg 0..3 granules]     16KB

  const int tid = threadIdx.x;
  const int lane = tid & 63;
  const int q = lane & 31, h = lane >> 5;
  const int w = tid >> 6;
  const int b = blockIdx.y, s = blockIdx.z;
  const int qw = blockIdx.x * 256 + w * 32;
  const int kbeg = s * (N / SPLIT);

  const ushort* qrow = qf + ((size_t)b * N + qw + q) * D;
  const ushort* kfb = kf + (size_t)b * N * D;
  const ushort* vtb = vt + (size_t)b * D * N;
  ushort* pog = pob + (size_t)s * BN * D;
  float* mlg = mlb + (size_t)s * BN * 2;

  // persistent Q chunks 0..7 (d 0..127); chunks 8..15 streamed per tile
  f16x8 qfr[8];
#pragma unroll
  for (int c = 0; c < 8; ++c)
    qfr[c] = *(const f16x8*)(qrow + c * 16 + h * 8);

  f32x16 o[8];
#pragma unroll
  for (int dt = 0; dt < 8; ++dt)
#pragma unroll
    for (int r = 0; r < 16; ++r) o[dt][r] = 0.f;
  float m = -1e30f, lsum = 0.f;

  // stage one 32-key K+V tile; 4 granule-loads per thread (2 K + 2 V).
  // K: granule g -> key=g>>5, slot=g&31; content = global d-gran slot^(key&7)
  // V: granule g -> d=g>>2, sg=g&3;     content = global key-gran sg^(d&3)
  auto stage = [&](int bi, int k0) {
#pragma unroll
    for (int i = 0; i < 2; ++i) {
      const int g = i * 512 + tid;
      const int key = g >> 5, slot = g & 31;
      gload16(kfb + (size_t)(k0 + key) * D + ((slot ^ (key & 7)) * 8),
              &kbuf[bi][g * 8]);
    }
#pragma unroll
    for (int i = 0; i < 2; ++i) {
      const int g = i * 512 + tid;
      const int d = g >> 2, sg = g & 3;
      gload16(vtb + (size_t)d * N + k0 + ((sg ^ (d & 3)) * 8),
              &vbuf[bi][g * 8]);
    }
  };

  stage(0, kbeg);

  for (int t = 0; t < NTK; ++t) {
    const int cur = t % 3;
    // stream Q chunks 8..15 (issued BEFORE next-tile stage so vmcnt(12)
    // drains exactly the current tile's 4 stage loads)
    f16x8 qs[8];
#pragma unroll
    for (int c = 0; c < 8; ++c)
      qs[c] = *(const f16x8*)(qrow + (8 + c) * 16 + h * 8);
    if (t + 1 < NTK) {
      stage((t + 1) % 3, kbeg + (t + 1) * KVB);
      asm volatile("s_waitcnt vmcnt(12)" ::: "memory");  // drain stage(t)
    } else {
      asm volatile("s_waitcnt vmcnt(8)" ::: "memory");   // qs still in flight
    }
    __builtin_amdgcn_sched_barrier(0);
    __builtin_amdgcn_s_barrier();   // the ONLY barrier per tile
    __builtin_amdgcn_sched_barrier(0);

    // ---- S^T = K Q : one 32x32 C-tile, 2 partial-sum chains ----
    f32x16 pa, pb;
#pragma unroll
    for (int r = 0; r < 16; ++r) { pa[r] = 0.f; pb[r] = 0.f; }
    const int ksw = (q & 7);
    __builtin_amdgcn_s_setprio(1);
#pragma unroll
    for (int c = 0; c < 8; ++c) {
      const f16x8 ka = *(const f16x8*)&kbuf[cur][q * 256 +
                                                 (((c * 2 + h) ^ ksw) * 8)];
      const f16x8 kb_ = *(const f16x8*)&kbuf[cur][q * 256 +
                                                  ((((c + 8) * 2 + h) ^ ksw) * 8)];
      pa = mfma32(ka, qfr[c], pa);
      pb = mfma32(kb_, qs[c], pb);
    }
    __builtin_amdgcn_s_setprio(0);
    f32x16 p;
#pragma unroll
    for (int r = 0; r < 16; ++r) p[r] = pa[r] + pb[r];

    // ---- softmax: in-lane tree + cross-half shfl ----
    float tm[8];
#pragma unroll
    for (int j = 0; j < 8; ++j) tm[j] = fmaxf(p[2 * j], p[2 * j + 1]);
    float pmax = fmaxf(fmaxf(fmaxf(tm[0], tm[1]), fmaxf(tm[2], tm[3])),
                       fmaxf(fmaxf(tm[4], tm[5]), fmaxf(tm[6], tm[7])));
    const float pm = fmaxf(pmax, __shfl_xor(pmax, 32));
    const bool need = pm > m + THR;
    if (__any(need)) {
      const float mn = fmaxf(m, pm);
      const float f = exp2f(m - mn);
      m = mn;
      lsum *= f;
#pragma unroll
      for (int dt = 0; dt < 8; ++dt) o[dt] *= f;
    }
#pragma unroll
    for (int r = 0; r < 16; ++r) {
      p[r] = exp2f(p[r] - m);
      lsum += p[r];
    }

    // ---- pack P -> 2 PV B-frags (16 keys each) via cvt_pkrtz + shfl ----
    // lane(q,h) owns packed words: x=keys(4h,4h+1) z=(4h+2,4h+3)
    // y=(8+4h,9+4h) wv=(10+4h,11+4h). B-frag word_j = keys(h*8+2j,+1):
    // word0 = h? partner-y : x ; word1 = h? partner-wv : z ;
    // word2 = h? y : partner-x ; word3 = h? wv : partner-z.
    f16x8 pf[2];
#pragma unroll
    for (int kk = 0; kk < 2; ++kk) {
      const int sub = kk * 8;
      unsigned x = pkh(p[sub + 0], p[sub + 1]);
      unsigned z = pkh(p[sub + 2], p[sub + 3]);
      unsigned y = pkh(p[sub + 4], p[sub + 5]);
      unsigned wv = pkh(p[sub + 6], p[sub + 7]);
      const unsigned xs = __shfl_xor(x, 32);
      const unsigned zs = __shfl_xor(z, 32);
      const unsigned ys = __shfl_xor(y, 32);
      const unsigned ws = __shfl_xor(wv, 32);
      union { f16x8 v; unsigned u[4]; } pu;
      pu.u[0] = h ? ys : x;
      pu.u[1] = h ? ws : z;
      pu.u[2] = h ? y : xs;
      pu.u[3] = h ? wv : zs;
      pf[kk] = pu.v;
    }

    // ---- O^T += V^T P^T : 8 d-tiles x 2 key-chunks ----
    __builtin_amdgcn_s_setprio(1);
#pragma unroll
    for (int dt = 0; dt < 8; ++dt) {
      const int d = dt * 32 + q;
      const int dsw = d & 3;
#pragma unroll
      for (int kk = 0; kk < 2; ++kk) {
        const f16x8 vf = *(const f16x8*)&vbuf[cur][d * 32 +
                                                   (((kk * 2 + h) ^ dsw) * 8)];
        o[dt] = mfma32(vf, pf[kk], o[dt]);
      }
    }
    __builtin_amdgcn_s_setprio(0);
    // NO end-of-tile barrier: triple buffering makes stage(t+1) safe.
  }

  // ---- epilogue: cross-half lsum, normalize, write O (row = qw+q) ----
  const float lt = lsum + __shfl_xor(lsum, 32);
  const float inv = 1.0f / lt;
  ushort* orow = pog + ((size_t)b * N + qw + q) * D;
#pragma unroll
  for (int dt = 0; dt < 8; ++dt)
#pragma unroll
    for (int r4 = 0; r4 < 4; ++r4) {
      const unsigned u0 =
          pkh(o[dt][r4 * 4 + 0] * inv, o[dt][r4 * 4 + 1] * inv);
      const unsigned u1 =
          pkh(o[dt][r4 * 4 + 2] * inv, o[dt][r4 * 4 + 3] * inv);
      uint2 val;
      val.x = u0;
      val.y = u1;
      *(uint2*)(orow + dt * 32 + r4 * 8 + h * 4) = val;
    }
  if (h == 0) {
    const size_t r = (size_t)b * N + qw + q;
    mlg[r * 2] = m;
    mlg[r * 2 + 1] = lt;
  }
}

// ---------------- merge KV-split partials -> f16 hi/lo planes --------------
__global__ __launch_bounds__(256) void merge_kernel(
    const ushort* __restrict__ pob, const float* __restrict__ mlb,
    ushort* __restrict__ aoh, ushort* __restrict__ aol) {
  const int t = threadIdx.x;
  const int row = blockIdx.x * 8 + (t >> 5);
  const int d0 = (t & 31) * 8;
  float mv[SPLIT], lv[SPLIT];
  float mm = -1e30f;
#pragma unroll
  for (int s = 0; s < SPLIT; ++s) {
    mv[s] = mlb[(size_t)s * BN * 2 + row * 2];
    lv[s] = mlb[(size_t)s * BN * 2 + row * 2 + 1];
    mm = fmaxf(mm, mv[s]);
  }
  float wsum = 0.f, a[SPLIT];
#pragma unroll
  for (int s = 0; s < SPLIT; ++s) {
    a[s] = exp2f(mv[s] - mm) * lv[s];
    wsum += a[s];
  }
  const float invw = 1.0f / wsum;
  const size_t off = (size_t)row * D + d0;
  float r[8] = {};
#pragma unroll
  for (int s = 0; s < SPLIT; ++s) {
    const f16x8 p = *(const f16x8*)(pob + (size_t)s * BN * D + off);
    const float c = a[s] * invw;
#pragma unroll
    for (int j = 0; j < 8; ++j) r[j] += c * (float)p[j];
  }
  f16x8 rh, rl;
#pragma unroll
  for (int j = 0; j < 8; ++j) {
    rh[j] = (_Float16)r[j];
    rl[j] = (_Float16)(r[j] - (float)rh[j]);
  }
  *(f16x8*)(aoh + off) = rh;
  *(f16x8*)(aol + off) = rl;
}

// ---------------- output projection via MFMA (no LDS) ----------------
__global__ __launch_bounds__(256, 4) void proj_kernel(
    const ushort* __restrict__ aoh, const ushort* __restrict__ aol,
    const ushort* __restrict__ wot, const float* __restrict__ bias,
    float* __restrict__ out) {
  const int t = threadIdx.x;
  const int w = t >> 6, lane = t & 63;
  const int lrow = lane & 15, lhi = lane >> 4;
  const int m0 = blockIdx.x * 128 + w * 32;
  const int c0 = blockIdx.y * 64;
  f32x4 acc[2][4];
#pragma unroll
  for (int qs = 0; qs < 2; ++qs)
#pragma unroll
    for (int nt = 0; nt < 4; ++nt) acc[qs][nt] = f32x4{0.f, 0.f, 0.f, 0.f};

#pragma unroll
  for (int kc = 0; kc < D; kc += 32) {
    f16x8 ah[2], al[2], bw[4];
#pragma unroll
    for (int qs = 0; qs < 2; ++qs) {
      const size_t ao = (size_t)(m0 + qs * 16 + lrow) * D + kc + lhi * 8;
      ah[qs] = *(const f16x8*)(aoh + ao);
      al[qs] = *(const f16x8*)(aol + ao);
    }
#pragma unroll
    for (int nt = 0; nt < 4; ++nt)
      bw[nt] = *(const f16x8*)(wot + (size_t)(c0 + nt * 16 + lrow) * D + kc +
                               lhi * 8);
#pragma unroll
    for (int qs = 0; qs < 2; ++qs)
#pragma unroll
      for (int nt = 0; nt < 4; ++nt) {
        acc[qs][nt] = mfma_f16(ah[qs], bw[nt], acc[qs][nt]);
        acc[qs][nt] = mfma_f16(al[qs], bw[nt], acc[qs][nt]);
      }
  }
#pragma unroll
  for (int qs = 0; qs < 2; ++qs)
#pragma unroll
    for (int nt = 0; nt < 4; ++nt)
#pragma unroll
      for (int i = 0; i < 4; ++i) {
        const int row = m0 + qs * 16 + lhi * 4 + i;
        const int col = c0 + nt * 16 + lrow;
        out[(size_t)row * D + col] = acc[qs][nt][i] + bias[col];
      }
}

extern "C" void kernel_launch(void* const* d_in, const int* in_sizes, int n_in,
                              void* d_out, int out_size, void* d_ws, size_t ws_size,
                              hipStream_t stream) {
  const float* x = (const float*)d_in[0];
  const float* coord = (const float*)d_in[1];
  const float* ln_g = (const float*)d_in[2];
  const float* ln_b = (const float*)d_in[3];
  const float* w_qkv = (const float*)d_in[4];
  const float* w_out = (const float*)d_in[5];
  const float* b_out = (const float*)d_in[6];
  float* out = (float*)d_out;

  const size_t P = (size_t)BN * D;

  ushort* qfp = (ushort*)d_ws;
  ushort* kfp = qfp + P;
  ushort* vtp = kfp + P;
  ushort* pob = vtp + P;                      // SPLIT partial-O planes
  float* mlb = (float*)(pob + (size_t)SPLIT * P);
  ushort* wt = (ushort*)(mlb + (size_t)SPLIT * BN * 2);
  ushort* wot = wt + 768 * 256;
  // aliases (liveness-disjoint):
  ushort* nxh = pob;       // written by ln, consumed by qkv, dead before attn
  ushort* nxl = pob + P;
  ushort* aoh = qfp;       // written by merge after q/k are dead
  ushort* aol = kfp;

  hipLaunchKernelGGL(ln_kernel, dim3(BN), dim3(256), 0, stream,
                     x, ln_g, ln_b, nxh, nxl);
  hipLaunchKernelGGL(castw_kernel, dim3(1024), dim3(256), 0, stream,
                     w_qkv, w_out, wt, wot);
  hipLaunchKernelGGL(qkv_kernel, dim3(BN / 128, 12), dim3(256), 0, stream,
                     nxh, nxl, wt, coord, qfp, kfp, vtp);
  hipLaunchKernelGGL(attn_kernel, dim3(N / 256, B, SPLIT), dim3(512), 0,
                     stream, qfp, kfp, vtp, pob, mlb);
  hipLaunchKernelGGL(merge_kernel, dim3(BN / 8), dim3(256), 0, stream,
                     pob, mlb, aoh, aol);
  hipLaunchKernelGGL(proj_kernel, dim3(BN / 128, 4), dim3(256), 0, stream,
                     aoh, aol, wot, b_out, out);
}